// Round 9
// baseline (559.089 us; speedup 1.0000x reference)
//
#include <hip/hip_runtime.h>
#include <hip/hip_fp16.h>

typedef _Float16 f16;
typedef _Float16 f16x8 __attribute__((ext_vector_type(8)));
typedef _Float16 f16x4 __attribute__((ext_vector_type(4)));
typedef float    f32x4 __attribute__((ext_vector_type(4)));

#define AS1 __attribute__((address_space(1)))
#define AS3 __attribute__((address_space(3)))

// async 16B global->LDS DMA: LDS dest is wave-uniform base + lane*16.
__device__ __forceinline__ void gl_lds16(const void* g, void* l) {
    __builtin_amdgcn_global_load_lds((const AS1 unsigned int*)g,
                                     (AS3 unsigned int*)l, 16, 0, 0);
}

#define NB   8
#define NN   32
#define NT   64
#define ND   64
#define NK   4
#define NH   256
#define NSO  256
#define NE   992
#define TOUT 63
#define M1   (NB*TOUT*NN)   // 16128 node-time rows
#define NBT  (NB*TOUT)      // 504 (b,t) pairs

// ---- workspace layout (bytes) ----
static constexpr size_t SZ_RS   = (size_t)M1 * 1024 * 2;        // 33,030,144
static constexpr size_t OFF_R   = 0;
static constexpr size_t OFF_S   = OFF_R + SZ_RS;
static constexpr size_t OFF_W2T = OFF_S + SZ_RS;                // f16 [k][co][h] 524,288
static constexpr size_t OFF_WF1 = OFF_W2T + 4*256*256*2;        // f16 [co][d(320)]
static constexpr size_t OFF_WF2 = OFF_WF1 + 256*320*2;
static constexpr size_t OFF_WF3 = OFF_WF2 + 256*256*2;
static constexpr size_t OFF_REL = OFF_WF3 + 64*256*2;           // f32 [b][ns][k][32]
static constexpr size_t OFF_AGG = OFF_REL + (size_t)NB*NN*NK*32*4; // f32 [m][256] 16,515,072
static constexpr size_t OFF_W1T = OFF_AGG + (size_t)M1*256*4;   // f16 [c(2048)][d(64)]
// total = OFF_W1T + 262,144 = 83,820,544 bytes

// ============================ K0: weight prep + AGG zero ============================
__global__ __launch_bounds__(256) void k0_prep(
    const float* __restrict__ W1, const float* __restrict__ W2,
    const float* __restrict__ Wf1, const float* __restrict__ Wf2,
    const float* __restrict__ Wf3, const float* __restrict__ rel,
    f16* __restrict__ W1T, f16* __restrict__ W2T, f16* __restrict__ Wf1T,
    f16* __restrict__ Wf2T, f16* __restrict__ Wf3T, float* __restrict__ REL,
    unsigned int* __restrict__ AGGZ)
{
    int id = blockIdx.x * 256 + threadIdx.x;
    if (id < 262144) {                      // W2T[k][co][h] = W2[k][h][co]
        int k = id >> 16, co = (id >> 8) & 255, h = id & 255;
        W2T[id] = (f16)W2[k*65536 + h*256 + co];
    } else if (id < 344064) {               // Wf1T[co][d] = Wf1[d][co], d<320
        int i = id - 262144; int co = i / 320, d = i % 320;
        Wf1T[i] = (f16)Wf1[d*256 + co];
    } else if (id < 409600) {               // Wf2T[co][h] = Wf2[h][co]
        int i = id - 344064; int co = i >> 8, h = i & 255;
        Wf2T[i] = (f16)Wf2[h*256 + co];
    } else if (id < 425984) {               // Wf3T[d][h] = Wf3[h][d], d<64
        int i = id - 409600; int d = i >> 8, h = i & 255;
        Wf3T[i] = (f16)Wf3[h*64 + d];
    } else if (id < 458752) {               // REL[b][ns][k][j], self-edge -> 0
        int i = id - 425984;
        int j = i & 31, k = (i >> 5) & 3, ns = (i >> 7) & 31, b = i >> 12;
        float v = 0.f;
        if (j != ns) v = rel[(b*NE + ns*31 + (j < ns ? j : j - 1))*NK + k];
        REL[i] = v;
    } else {                                // W1T[c][d] = W1[k][dd*64+d][h] (131072 elems)
        int i = id - 458752;
        int c = i >> 6, d = i & 63;
        int k = c >> 9, dd = (c >> 8) & 1, h = c & 255;
        W1T[i] = (f16)W1[(k*128 + dd*64 + d)*NH + h];
    }
    // zero AGG (f32): 4,128,768 dwords = 7 x 589,824 threads exactly
    #pragma unroll
    for (int j = 0; j < 7; ++j) {
        int idx = id + j*589824;
        if (idx < 4128768) AGGZ[idx] = 0u;
    }
}

// ============ K1: per-node layer-1 partials R,S (MFMA, f16) ============
// Rb/Sb rows stored with each 64-f16 sub-block's 16B chunks swizzled by n&7
// (n = node = m&31) so k2's LDS reads at chunk^(row&7) are conflict-free.
__global__ __launch_bounds__(256) void k1_partials(
    const float* __restrict__ inputs, const f16* __restrict__ W1T,
    const float* __restrict__ b1, f16* __restrict__ Rb, f16* __restrict__ Sb)
{
    __shared__ __align__(16) f16 xs[64][72];
    __shared__ __align__(16) f16 wl[256][72];
    int tid = threadIdx.x;
    int w = tid >> 6, lane = tid & 63, ln = lane & 15, q = lane >> 4;
    int m0 = blockIdx.x * 64;

    #pragma unroll
    for (int it = 0; it < 2; ++it) {             // stage x -> f16
        int idx8 = it*256 + tid;
        int m = idx8 >> 3, hs = idx8 & 7;
        int mrow = m0 + m;
        int b = mrow / 2016, r2 = mrow % 2016, t = r2 >> 5, n = r2 & 31;
        const float* px = &inputs[((b*NN + n)*NT + t)*ND + hs*8];
        f32x4 v0 = *(const f32x4*)px, v1 = *(const f32x4*)(px + 4);
        f16x8 o;
        #pragma unroll
        for (int e = 0; e < 4; ++e) { o[e] = (f16)v0[e]; o[e+4] = (f16)v1[e]; }
        *(f16x8*)&xs[m][hs*8] = o;
    }
    const f32x4 z4 = {0.f, 0.f, 0.f, 0.f};
    for (int cc = 0; cc < 8; ++cc) {             // 8 chunks of 256 output cols
        int k = cc >> 1, dd = cc & 1;
        __syncthreads();
        #pragma unroll
        for (int it = 0; it < 8; ++it) {
            int idx8 = it*256 + tid;
            int co = idx8 >> 3, seg = idx8 & 7;
            *(f16x8*)&wl[co][seg*8] = *(const f16x8*)&W1T[(size_t)(cc*256 + co)*64 + seg*8];
        }
        __syncthreads();
        f32x4 acc[16];
        #pragma unroll
        for (int nt = 0; nt < 16; ++nt) acc[nt] = z4;
        #pragma unroll
        for (int ks = 0; ks < 2; ++ks) {
            f16x8 Af = *(const f16x8*)&xs[w*16 + ln][ks*32 + q*8];
            #pragma unroll
            for (int nt = 0; nt < 16; ++nt) {
                f16x8 Bf = *(const f16x8*)&wl[nt*16 + ln][ks*32 + q*8];
                acc[nt] = __builtin_amdgcn_mfma_f32_16x16x32_f16(Af, Bf, acc[nt], 0, 0, 0);
            }
        }
        __syncthreads();
        f16* ob = &wl[0][0];                      // out-stage, stride 264
        #pragma unroll
        for (int nt = 0; nt < 16; ++nt) {
            int co = nt*16 + ln;
            float bias = dd ? b1[k*NH + co] : 0.f;
            #pragma unroll
            for (int r = 0; r < 4; ++r) {
                float v = acc[nt][r] + bias;
                ob[(w*16 + q*4 + r)*264 + co] = (f16)v;
            }
        }
        __syncthreads();
        f16* dst = dd ? Sb : Rb;
        #pragma unroll
        for (int it = 0; it < 8; ++it) {          // swizzled coalesced stores
            int idx8 = it*256 + tid;
            int m = idx8 >> 5, seg = idx8 & 31;
            int hcb = seg >> 3, c = seg & 7;
            *(f16x8*)&dst[(size_t)(m0 + m)*1024 + k*256 + hcb*64 + c*8] =
                *(const f16x8*)&ob[m*264 + hcb*64 + (((c ^ (m & 7))) << 3)];
        }
    }
}

// ============ K2: edge MLP layer-2, W2 in REGISTERS, barrier-light ============
// Block = (k, bt-chunk of 4): grid 504, 256 thr (4 waves = 4 ng), 2 blocks/CU.
// Per ibt (one bt): stage ALL 32 R rows AND ALL 32 S rows (32 KB) via DMA,
// then run the 16 nsp tiles BARRIER-FREE (R,S stable in LDS; W2 in regs).
// Barriers: 4 per block (was 64) -- the round-8 stall analysis showed ~55%
// idle from per-tile barrier coupling at 2 waves/SIMD.
// Per lane: Breg 128 + acc 64; cap 256 via (256,2). LDS 64 KB -> 2 blocks/CU.
__global__ __launch_bounds__(256, 2) void k2_edge(
    const f16* __restrict__ Rb, const f16* __restrict__ Sb,
    const f16* __restrict__ W2T, const float* __restrict__ b2,
    const float* __restrict__ REL, float* __restrict__ AGG)
{
    __shared__ __align__(16) f16 Rbuf[2][32*256];   // 16 KB per buf
    __shared__ __align__(16) f16 Sbuf[2][32*256];   // 16 KB per buf
    int tid = threadIdx.x;
    int blk = blockIdx.x;
    int k = blk & 3, g = blk >> 2;               // g in 0..125 -> bt = g*4..g*4+3
    int ng = tid >> 6, lane = tid & 63, ln = lane & 15, q = lane >> 4;
    int lrow = lane >> 5, lseg = lane & 31;      // DMA: 2 rows x 32 chunks per call

    // ---- W2(k) fragments in registers + bias ----
    f16x8 Breg[4][8];
    float bias[4];
    #pragma unroll
    for (int nt = 0; nt < 4; ++nt) {
        int co = ng*64 + nt*16 + ln;
        bias[nt] = b2[k*256 + co];
        const f16* wrow = &W2T[(size_t)(k*256 + co)*256];
        #pragma unroll
        for (int ks = 0; ks < 8; ++ks)
            Breg[nt][ks] = *(const f16x8*)&wrow[ks*32 + q*8];
    }

    auto stageRS = [&](int bt, int buf) {        // 32 KB: 8 DMA calls per wave
        #pragma unroll
        for (int it = 0; it < 4; ++it) {
            int rowbase = ng*8 + it*2;
            size_t goff = ((size_t)bt*NN + rowbase + lrow)*1024 + k*256 + lseg*8;
            gl_lds16(&Rb[goff], &Rbuf[buf][rowbase*256 + lane*8]);
            gl_lds16(&Sb[goff], &Sbuf[buf][rowbase*256 + lane*8]);
        }
    };

    stageRS(g*4, 0);
    __syncthreads();

    const f32x4 z4 = {0.f, 0.f, 0.f, 0.f};
    const f16x8 zf = {0,0,0,0,0,0,0,0};
    for (int ibt = 0; ibt < 4; ++ibt) {
        int bt = g*4 + ibt, b = bt / TOUT;
        int buf = ibt & 1;
        if (ibt < 3) stageRS(bt + 1, buf ^ 1);   // 16 tiles of compute to hide it
        const f16* Rl = &Rbuf[buf][0];
        const f16* Sl = &Sbuf[buf][0];

        for (int nsp = 0; nsp < 16; ++nsp) {     // barrier-free inner loop
            int ns0 = nsp*2;                     // senders ns0, ns0+1
            f32x4 acc[4][4];
            #pragma unroll
            for (int mt = 0; mt < 4; ++mt)
                #pragma unroll
                for (int nt = 0; nt < 4; ++nt) acc[mt][nt] = z4;

            #pragma unroll
            for (int ks = 0; ks < 8; ++ks) {
                int hc = ks >> 1;
                int c4 = (ks & 1)*4 + q;
                int paR = hc*64 + ((c4 ^ (ln & 7)) << 3);
                f16x8 rlo = *(const f16x8*)&Rl[ln*256 + paR];
                f16x8 rhi = *(const f16x8*)&Rl[(16 + ln)*256 + paR];
                f16x8 s0 = *(const f16x8*)&Sl[(ns0 + 0)*256 + hc*64 + ((c4 ^ (ns0 & 7)) << 3)];
                f16x8 s1 = *(const f16x8*)&Sl[(ns0 + 1)*256 + hc*64 + ((c4 ^ ((ns0 + 1) & 7)) << 3)];
                f16x8 A[4];
                A[0] = __builtin_elementwise_max(rlo + s0, zf);   // sender0, rows 0-15
                A[1] = __builtin_elementwise_max(rhi + s0, zf);   // sender0, rows 16-31
                A[2] = __builtin_elementwise_max(rlo + s1, zf);   // sender1, rows 0-15
                A[3] = __builtin_elementwise_max(rhi + s1, zf);   // sender1, rows 16-31
                #pragma unroll
                for (int nt = 0; nt < 4; ++nt) {
                    f16x8 Bf = Breg[nt][ks];
                    #pragma unroll
                    for (int mt = 0; mt < 4; ++mt)
                        acc[mt][nt] = __builtin_amdgcn_mfma_f32_16x16x32_f16(
                            A[mt], Bf, acc[mt][nt], 0, 0, 0);
                }
            }
            // epilogue: bias+relu, rel-weight, reduce over 32 j, f32 atomic add
            #pragma unroll
            for (int half = 0; half < 2; ++half) {
                int ns = ns0 + half;
                const float* relp = &REL[(((size_t)b*NN + ns)*NK + k)*32];
                f32x4 rel0 = *(const f32x4*)&relp[q*4];
                f32x4 rel1 = *(const f32x4*)&relp[16 + q*4];
                #pragma unroll
                for (int nt = 0; nt < 4; ++nt) {
                    float s = 0.f;
                    #pragma unroll
                    for (int r = 0; r < 4; ++r) {
                        float v0 = acc[2*half + 0][nt][r] + bias[nt];
                        float v1 = acc[2*half + 1][nt][r] + bias[nt];
                        v0 = v0 > 0.f ? v0 : 0.f;
                        v1 = v1 > 0.f ? v1 : 0.f;
                        s += v0 * rel0[r] + v1 * rel1[r];
                    }
                    s += __shfl_xor(s, 16);
                    s += __shfl_xor(s, 32);
                    if (lane < 16)
                        atomicAdd(&AGG[((size_t)bt*NN + ns)*256 + ng*64 + nt*16 + lane], s);
                }
            }
        }
        __syncthreads();   // drains next-ibt DMA; protects buf reuse at ibt+2
    }
}

// ============ K3: node MLP (320->256->256->64) + residual ============
__global__ __launch_bounds__(256) void k3_node(
    const float* __restrict__ inputs, const float* __restrict__ AGG,
    const f16* __restrict__ Wf1T, const float* __restrict__ bf1,
    const f16* __restrict__ Wf2T, const float* __restrict__ bf2,
    const f16* __restrict__ Wf3T, const float* __restrict__ bf3,
    float* __restrict__ out)
{
    __shared__ __align__(16) f16 aug[64][328];
    __shared__ __align__(16) f16 p1[64][264];
    __shared__ __align__(16) f16 wl[256][72];
    int tid = threadIdx.x;
    int w = tid >> 6, lane = tid & 63, ln = lane & 15, q = lane >> 4;
    int m0 = blockIdx.x * 64;

    for (int it = 0; it < 10; ++it) {       // stage aug = [x | agg]
        int s = it*256 + tid;
        if (s < 512) {
            int m = s >> 3, hs = s & 7;
            int mrow = m0 + m;
            int b = mrow / 2016, r2 = mrow % 2016, t = r2 >> 5, n = r2 & 31;
            const float* px = &inputs[((b*NN + n)*NT + t)*ND + hs*8];
            f32x4 v0 = *(const f32x4*)px, v1 = *(const f32x4*)(px + 4);
            f16x8 o;
            #pragma unroll
            for (int e = 0; e < 4; ++e) { o[e] = (f16)v0[e]; o[e+4] = (f16)v1[e]; }
            *(f16x8*)&aug[m][hs*8] = o;
        } else {
            int s2 = s - 512;
            int m = s2 >> 5, hs = s2 & 31;
            const float* pa = &AGG[(size_t)(m0 + m)*NSO + hs*8];
            f32x4 v0 = *(const f32x4*)pa, v1 = *(const f32x4*)(pa + 4);
            f16x8 o;
            #pragma unroll
            for (int e = 0; e < 4; ++e) { o[e] = (f16)v0[e]; o[e+4] = (f16)v1[e]; }
            *(f16x8*)&aug[m][64 + hs*8] = o;
        }
    }
    const f32x4 z4 = {0.f, 0.f, 0.f, 0.f};
    // ---- layer 1: K=320 ----
    f32x4 acc1[16];
    #pragma unroll
    for (int nt = 0; nt < 16; ++nt) acc1[nt] = z4;
    for (int hc = 0; hc < 5; ++hc) {
        __syncthreads();
        #pragma unroll
        for (int it = 0; it < 8; ++it) {
            int idx8 = it*256 + tid;
            int co = idx8 >> 3, seg = idx8 & 7;
            *(f16x8*)&wl[co][seg*8] = *(const f16x8*)&Wf1T[co*320 + hc*64 + seg*8];
        }
        __syncthreads();
        #pragma unroll
        for (int ks = 0; ks < 2; ++ks) {
            f16x8 Af = *(const f16x8*)&aug[w*16 + ln][hc*64 + ks*32 + q*8];
            #pragma unroll
            for (int nt = 0; nt < 16; ++nt) {
                f16x8 Bf = *(const f16x8*)&wl[nt*16 + ln][ks*32 + q*8];
                acc1[nt] = __builtin_amdgcn_mfma_f32_16x16x32_f16(Af, Bf, acc1[nt], 0, 0, 0);
            }
        }
    }
    #pragma unroll
    for (int nt = 0; nt < 16; ++nt) {
        int co = nt*16 + ln;
        float bias = bf1[co];
        #pragma unroll
        for (int r = 0; r < 4; ++r) {
            float v = acc1[nt][r] + bias; v = v > 0.f ? v : 0.f;
            p1[w*16 + q*4 + r][co] = (f16)v;
        }
    }
    // ---- layer 2: K=256 ----
    f32x4 acc2[16];
    #pragma unroll
    for (int nt = 0; nt < 16; ++nt) acc2[nt] = z4;
    for (int hc = 0; hc < 4; ++hc) {
        __syncthreads();
        #pragma unroll
        for (int it = 0; it < 8; ++it) {
            int idx8 = it*256 + tid;
            int co = idx8 >> 3, seg = idx8 & 7;
            *(f16x8*)&wl[co][seg*8] = *(const f16x8*)&Wf2T[co*256 + hc*64 + seg*8];
        }
        __syncthreads();
        #pragma unroll
        for (int ks = 0; ks < 2; ++ks) {
            f16x8 Af = *(const f16x8*)&p1[w*16 + ln][hc*64 + ks*32 + q*8];
            #pragma unroll
            for (int nt = 0; nt < 16; ++nt) {
                f16x8 Bf = *(const f16x8*)&wl[nt*16 + ln][ks*32 + q*8];
                acc2[nt] = __builtin_amdgcn_mfma_f32_16x16x32_f16(Af, Bf, acc2[nt], 0, 0, 0);
            }
        }
    }
    f16* p2 = &aug[0][0];    // reuse aug storage, stride 264
    #pragma unroll
    for (int nt = 0; nt < 16; ++nt) {
        int co = nt*16 + ln;
        float bias = bf2[co];
        #pragma unroll
        for (int r = 0; r < 4; ++r) {
            float v = acc2[nt][r] + bias; v = v > 0.f ? v : 0.f;
            p2[(w*16 + q*4 + r)*264 + co] = (f16)v;
        }
    }
    __syncthreads();
    // ---- layer 3: K=256, N=64 ----
    f16* w3 = &wl[0][0];
    #pragma unroll
    for (int it = 0; it < 8; ++it) {
        int idx8 = it*256 + tid;
        int d = idx8 >> 5, seg = idx8 & 31;
        *(f16x8*)&w3[d*264 + seg*8] = *(const f16x8*)&Wf3T[d*256 + seg*8];
    }
    __syncthreads();
    f32x4 acc3[4];
    #pragma unroll
    for (int nt = 0; nt < 4; ++nt) acc3[nt] = z4;
    #pragma unroll
    for (int ks = 0; ks < 8; ++ks) {
        f16x8 Af = *(const f16x8*)&p2[(w*16 + ln)*264 + ks*32 + q*8];
        #pragma unroll
        for (int nt = 0; nt < 4; ++nt) {
            f16x8 Bf = *(const f16x8*)&w3[(nt*16 + ln)*264 + ks*32 + q*8];
            acc3[nt] = __builtin_amdgcn_mfma_f32_16x16x32_f16(Af, Bf, acc3[nt], 0, 0, 0);
        }
    }
    #pragma unroll
    for (int nt = 0; nt < 4; ++nt) {
        int d = nt*16 + ln;
        float bias = bf3[d];
        #pragma unroll
        for (int r = 0; r < 4; ++r) {
            int mrow = m0 + w*16 + q*4 + r;
            int b = mrow / 2016, r2 = mrow % 2016, t = r2 >> 5, n = r2 & 31;
            float xv = inputs[((b*NN + n)*NT + t)*ND + d];
            out[((size_t)(b*NN + n)*TOUT + t)*ND + d] = acc3[nt][r] + bias + xv;
        }
    }
}

extern "C" void kernel_launch(void* const* d_in, const int* in_sizes, int n_in,
                              void* d_out, int out_size, void* d_ws, size_t ws_size,
                              hipStream_t stream)
{
    const float* inputs = (const float*)d_in[0];
    const float* rel    = (const float*)d_in[1];
    const float* W1     = (const float*)d_in[4];
    const float* b1     = (const float*)d_in[5];
    const float* W2     = (const float*)d_in[6];
    const float* b2     = (const float*)d_in[7];
    const float* Wf1    = (const float*)d_in[8];
    const float* bf1    = (const float*)d_in[9];
    const float* Wf2    = (const float*)d_in[10];
    const float* bf2    = (const float*)d_in[11];
    const float* Wf3    = (const float*)d_in[12];
    const float* bf3    = (const float*)d_in[13];
    char* ws = (char*)d_ws;
    f16*   Rb   = (f16*)(ws + OFF_R);
    f16*   Sb   = (f16*)(ws + OFF_S);
    f16*   W2T  = (f16*)(ws + OFF_W2T);
    f16*   Wf1T = (f16*)(ws + OFF_WF1);
    f16*   Wf2T = (f16*)(ws + OFF_WF2);
    f16*   Wf3T = (f16*)(ws + OFF_WF3);
    float* REL  = (float*)(ws + OFF_REL);
    float* AGG  = (float*)(ws + OFF_AGG);
    f16*   W1T  = (f16*)(ws + OFF_W1T);
    float* out  = (float*)d_out;

    hipLaunchKernelGGL(k0_prep, dim3(2304), dim3(256), 0, stream,
                       W1, W2, Wf1, Wf2, Wf3, rel, W1T, W2T, Wf1T, Wf2T, Wf3T, REL,
                       (unsigned int*)AGG);
    hipLaunchKernelGGL(k1_partials, dim3(252), dim3(256), 0, stream,
                       inputs, W1T, b1, Rb, Sb);
    hipLaunchKernelGGL(k2_edge, dim3(504), dim3(256), 0, stream,
                       Rb, Sb, W2T, b2, REL, AGG);
    hipLaunchKernelGGL(k3_node, dim3(252), dim3(256), 0, stream,
                       inputs, AGG, Wf1T, bf1, Wf2T, bf2, Wf3T, bf3, out);
}

// Round 10
// 549.507 us; speedup vs baseline: 1.0174x; 1.0174x over previous
//
#include <hip/hip_runtime.h>
#include <hip/hip_fp16.h>

typedef _Float16 f16;
typedef _Float16 f16x8 __attribute__((ext_vector_type(8)));
typedef _Float16 f16x4 __attribute__((ext_vector_type(4)));
typedef float    f32x4 __attribute__((ext_vector_type(4)));

#define AS1 __attribute__((address_space(1)))
#define AS3 __attribute__((address_space(3)))

// async 16B global->LDS DMA: LDS dest is wave-uniform base + lane*16.
__device__ __forceinline__ void gl_lds16(const void* g, void* l) {
    __builtin_amdgcn_global_load_lds((const AS1 unsigned int*)g,
                                     (AS3 unsigned int*)l, 16, 0, 0);
}

#define NB   8
#define NN   32
#define NT   64
#define ND   64
#define NK   4
#define NH   256
#define NSO  256
#define NE   992
#define TOUT 63
#define M1   (NB*TOUT*NN)   // 16128 node-time rows
#define NBT  (NB*TOUT)      // 504 (b,t) pairs

// ---- workspace layout (bytes) ----
static constexpr size_t SZ_RS   = (size_t)M1 * 1024 * 2;        // 33,030,144
static constexpr size_t OFF_R   = 0;
static constexpr size_t OFF_S   = OFF_R + SZ_RS;
static constexpr size_t OFF_W2T = OFF_S + SZ_RS;                // f16 [k][co][h] 524,288
static constexpr size_t OFF_WF1 = OFF_W2T + 4*256*256*2;        // f16 [co][d(320)]
static constexpr size_t OFF_WF2 = OFF_WF1 + 256*320*2;
static constexpr size_t OFF_WF3 = OFF_WF2 + 256*256*2;
static constexpr size_t OFF_REL = OFF_WF3 + 64*256*2;           // f32 [b][ns][k][32]
static constexpr size_t OFF_AGG = OFF_REL + (size_t)NB*NN*NK*32*4; // f32 [m][256] 16,515,072
static constexpr size_t OFF_W1T = OFF_AGG + (size_t)M1*256*4;   // f16 [c(2048)][d(64)]
// total = OFF_W1T + 262,144 = 83,820,544 bytes

// ============================ K0: weight prep + AGG zero ============================
__global__ __launch_bounds__(256) void k0_prep(
    const float* __restrict__ W1, const float* __restrict__ W2,
    const float* __restrict__ Wf1, const float* __restrict__ Wf2,
    const float* __restrict__ Wf3, const float* __restrict__ rel,
    f16* __restrict__ W1T, f16* __restrict__ W2T, f16* __restrict__ Wf1T,
    f16* __restrict__ Wf2T, f16* __restrict__ Wf3T, float* __restrict__ REL,
    unsigned int* __restrict__ AGGZ)
{
    int id = blockIdx.x * 256 + threadIdx.x;
    if (id < 262144) {                      // W2T[k][co][h] = W2[k][h][co]
        int k = id >> 16, co = (id >> 8) & 255, h = id & 255;
        W2T[id] = (f16)W2[k*65536 + h*256 + co];
    } else if (id < 344064) {               // Wf1T[co][d] = Wf1[d][co], d<320
        int i = id - 262144; int co = i / 320, d = i % 320;
        Wf1T[i] = (f16)Wf1[d*256 + co];
    } else if (id < 409600) {               // Wf2T[co][h] = Wf2[h][co]
        int i = id - 344064; int co = i >> 8, h = i & 255;
        Wf2T[i] = (f16)Wf2[h*256 + co];
    } else if (id < 425984) {               // Wf3T[d][h] = Wf3[h][d], d<64
        int i = id - 409600; int d = i >> 8, h = i & 255;
        Wf3T[i] = (f16)Wf3[h*64 + d];
    } else if (id < 458752) {               // REL[b][ns][k][j], self-edge -> 0
        int i = id - 425984;
        int j = i & 31, k = (i >> 5) & 3, ns = (i >> 7) & 31, b = i >> 12;
        float v = 0.f;
        if (j != ns) v = rel[(b*NE + ns*31 + (j < ns ? j : j - 1))*NK + k];
        REL[i] = v;
    } else {                                // W1T[c][d] = W1[k][dd*64+d][h] (131072 elems)
        int i = id - 458752;
        int c = i >> 6, d = i & 63;
        int k = c >> 9, dd = (c >> 8) & 1, h = c & 255;
        W1T[i] = (f16)W1[(k*128 + dd*64 + d)*NH + h];
    }
    // zero AGG (f32): 4,128,768 dwords = 7 x 589,824 threads exactly
    #pragma unroll
    for (int j = 0; j < 7; ++j) {
        int idx = id + j*589824;
        if (idx < 4128768) AGGZ[idx] = 0u;
    }
}

// ============ K1: per-node layer-1 partials R,S (MFMA, f16) ============
// Rb/Sb rows stored with each 64-f16 sub-block's 16B chunks swizzled by n&7
// (n = node = m&31) so k2's LDS reads at chunk^(row&7) are conflict-free.
__global__ __launch_bounds__(256) void k1_partials(
    const float* __restrict__ inputs, const f16* __restrict__ W1T,
    const float* __restrict__ b1, f16* __restrict__ Rb, f16* __restrict__ Sb)
{
    __shared__ __align__(16) f16 xs[64][72];
    __shared__ __align__(16) f16 wl[256][72];
    int tid = threadIdx.x;
    int w = tid >> 6, lane = tid & 63, ln = lane & 15, q = lane >> 4;
    int m0 = blockIdx.x * 64;

    #pragma unroll
    for (int it = 0; it < 2; ++it) {             // stage x -> f16
        int idx8 = it*256 + tid;
        int m = idx8 >> 3, hs = idx8 & 7;
        int mrow = m0 + m;
        int b = mrow / 2016, r2 = mrow % 2016, t = r2 >> 5, n = r2 & 31;
        const float* px = &inputs[((b*NN + n)*NT + t)*ND + hs*8];
        f32x4 v0 = *(const f32x4*)px, v1 = *(const f32x4*)(px + 4);
        f16x8 o;
        #pragma unroll
        for (int e = 0; e < 4; ++e) { o[e] = (f16)v0[e]; o[e+4] = (f16)v1[e]; }
        *(f16x8*)&xs[m][hs*8] = o;
    }
    const f32x4 z4 = {0.f, 0.f, 0.f, 0.f};
    for (int cc = 0; cc < 8; ++cc) {             // 8 chunks of 256 output cols
        int k = cc >> 1, dd = cc & 1;
        __syncthreads();
        #pragma unroll
        for (int it = 0; it < 8; ++it) {
            int idx8 = it*256 + tid;
            int co = idx8 >> 3, seg = idx8 & 7;
            *(f16x8*)&wl[co][seg*8] = *(const f16x8*)&W1T[(size_t)(cc*256 + co)*64 + seg*8];
        }
        __syncthreads();
        f32x4 acc[16];
        #pragma unroll
        for (int nt = 0; nt < 16; ++nt) acc[nt] = z4;
        #pragma unroll
        for (int ks = 0; ks < 2; ++ks) {
            f16x8 Af = *(const f16x8*)&xs[w*16 + ln][ks*32 + q*8];
            #pragma unroll
            for (int nt = 0; nt < 16; ++nt) {
                f16x8 Bf = *(const f16x8*)&wl[nt*16 + ln][ks*32 + q*8];
                acc[nt] = __builtin_amdgcn_mfma_f32_16x16x32_f16(Af, Bf, acc[nt], 0, 0, 0);
            }
        }
        __syncthreads();
        f16* ob = &wl[0][0];                      // out-stage, stride 264
        #pragma unroll
        for (int nt = 0; nt < 16; ++nt) {
            int co = nt*16 + ln;
            float bias = dd ? b1[k*NH + co] : 0.f;
            #pragma unroll
            for (int r = 0; r < 4; ++r) {
                float v = acc[nt][r] + bias;
                ob[(w*16 + q*4 + r)*264 + co] = (f16)v;
            }
        }
        __syncthreads();
        f16* dst = dd ? Sb : Rb;
        #pragma unroll
        for (int it = 0; it < 8; ++it) {          // swizzled coalesced stores
            int idx8 = it*256 + tid;
            int m = idx8 >> 5, seg = idx8 & 31;
            int hcb = seg >> 3, c = seg & 7;
            *(f16x8*)&dst[(size_t)(m0 + m)*1024 + k*256 + hcb*64 + c*8] =
                *(const f16x8*)&ob[m*264 + hcb*64 + (((c ^ (m & 7))) << 3)];
        }
    }
}

// ============ K2: edge MLP layer-2, W2 in REGISTERS, co-half split ============
// Block = (k, co-half, bt-chunk of 4): grid 1008, 256 thr, 3 blocks/CU.
// Round-8 per-tile DMA cadence (proven: per-ibt bursts serialize on vmcnt(0)
// -- round-9 regression). co-half split halves Breg(64)+acc(32) so
// __launch_bounds__(256,3) (170-reg cap) fits -> 12 waves/CU in 3 independent
// barrier domains (the round-8 stall was 2 coupled waves/SIMD).
// Bias pre-loaded into acc init (saves 64 VALU/tile in epilogue).
__global__ __launch_bounds__(256, 3) void k2_edge(
    const f16* __restrict__ Rb, const f16* __restrict__ Sb,
    const f16* __restrict__ W2T, const float* __restrict__ b2,
    const float* __restrict__ REL, float* __restrict__ AGG)
{
    __shared__ __align__(16) f16 Rbuf[2][32*256];   // 16 KB per buf
    __shared__ __align__(16) f16 Sbuf[2][2*256];    // 1 KB per buf
    int tid = threadIdx.x;
    int blk = blockIdx.x;
    int k = blk & 3, nh = (blk >> 2) & 1, g = blk >> 3;  // g in 0..125
    int ng = tid >> 6, lane = tid & 63, ln = lane & 15, q = lane >> 4;
    int lrow = lane >> 5, lseg = lane & 31;      // DMA: 2 rows x 32 chunks per call

    // ---- W2(k) fragments for this co-half in registers + bias ----
    f16x8 Breg[2][8];
    float bias[2];
    #pragma unroll
    for (int nt = 0; nt < 2; ++nt) {
        int co = nh*128 + ng*32 + nt*16 + ln;
        bias[nt] = b2[k*256 + co];
        const f16* wrow = &W2T[(size_t)(k*256 + co)*256];
        #pragma unroll
        for (int ks = 0; ks < 8; ++ks)
            Breg[nt][ks] = *(const f16x8*)&wrow[ks*32 + q*8];
    }

    auto stageR = [&](int bt, int buf) {         // 16 KB: 4 calls/wave x 4 waves
        #pragma unroll
        for (int it = 0; it < 4; ++it) {
            int rowbase = ng*8 + it*2;
            gl_lds16(&Rb[((size_t)bt*NN + rowbase + lrow)*1024 + k*256 + lseg*8],
                     &Rbuf[buf][rowbase*256 + lane*8]);
        }
    };
    auto stageS = [&](int i, int buf) {          // 1 KB: 1 call (wave 0)
        int bt = g*4 + (i >> 4), nsp = i & 15;
        if (ng == 0)
            gl_lds16(&Sb[((size_t)bt*NN + nsp*2 + lrow)*1024 + k*256 + lseg*8],
                     &Sbuf[buf][lane*8]);
    };

    stageR(g*4, 0);
    stageS(0, 0);
    __syncthreads();

    const f16x8 zf = {0,0,0,0,0,0,0,0};
    for (int i = 0; i < 64; ++i) {
        int ibt = i >> 4, nsp = i & 15;
        int bt = g*4 + ibt, b = bt / TOUT;
        int rb = ibt & 1, sb = i & 1;
        if (i < 63) stageS(i + 1, sb ^ 1);
        if (nsp == 14 && ibt < 3) stageR(bt + 1, rb ^ 1);

        const f16* Rl = &Rbuf[rb][0];
        const f16* Sl = &Sbuf[sb][0];
        int ns0 = nsp*2;                         // senders ns0, ns0+1
        f32x4 acc[4][2];
        #pragma unroll
        for (int mt = 0; mt < 4; ++mt)
            #pragma unroll
            for (int nt = 0; nt < 2; ++nt) {
                f32x4 binit = {bias[nt], bias[nt], bias[nt], bias[nt]};
                acc[mt][nt] = binit;
            }

        #pragma unroll
        for (int ks = 0; ks < 8; ++ks) {
            int hc = ks >> 1;
            int c4 = (ks & 1)*4 + q;
            int paR = hc*64 + ((c4 ^ (ln & 7)) << 3);
            f16x8 rlo = *(const f16x8*)&Rl[ln*256 + paR];
            f16x8 rhi = *(const f16x8*)&Rl[(16 + ln)*256 + paR];
            f16x8 s0 = *(const f16x8*)&Sl[0*256 + hc*64 + ((c4 ^ (ns0 & 7)) << 3)];
            f16x8 s1 = *(const f16x8*)&Sl[1*256 + hc*64 + ((c4 ^ ((ns0 + 1) & 7)) << 3)];
            f16x8 A[4];
            A[0] = __builtin_elementwise_max(rlo + s0, zf);   // sender0, rows 0-15
            A[1] = __builtin_elementwise_max(rhi + s0, zf);   // sender0, rows 16-31
            A[2] = __builtin_elementwise_max(rlo + s1, zf);   // sender1, rows 0-15
            A[3] = __builtin_elementwise_max(rhi + s1, zf);   // sender1, rows 16-31
            #pragma unroll
            for (int nt = 0; nt < 2; ++nt) {
                f16x8 Bf = Breg[nt][ks];
                #pragma unroll
                for (int mt = 0; mt < 4; ++mt)
                    acc[mt][nt] = __builtin_amdgcn_mfma_f32_16x16x32_f16(
                        A[mt], Bf, acc[mt][nt], 0, 0, 0);
            }
        }
        // epilogue: relu (bias already in acc), rel-weight, reduce 32 j, atomic
        #pragma unroll
        for (int half = 0; half < 2; ++half) {
            int ns = ns0 + half;
            const float* relp = &REL[(((size_t)b*NN + ns)*NK + k)*32];
            f32x4 rel0 = *(const f32x4*)&relp[q*4];
            f32x4 rel1 = *(const f32x4*)&relp[16 + q*4];
            #pragma unroll
            for (int nt = 0; nt < 2; ++nt) {
                float s = 0.f;
                #pragma unroll
                for (int r = 0; r < 4; ++r) {
                    float v0 = acc[2*half + 0][nt][r];
                    float v1 = acc[2*half + 1][nt][r];
                    v0 = v0 > 0.f ? v0 : 0.f;
                    v1 = v1 > 0.f ? v1 : 0.f;
                    s += v0 * rel0[r] + v1 * rel1[r];
                }
                s += __shfl_xor(s, 16);
                s += __shfl_xor(s, 32);
                if (lane < 16)
                    atomicAdd(&AGG[((size_t)bt*NN + ns)*256 + nh*128 + ng*32 + nt*16 + lane], s);
            }
        }
        __syncthreads();
    }
}

// ============ K3: node MLP (320->256->256->64) + residual ============
__global__ __launch_bounds__(256) void k3_node(
    const float* __restrict__ inputs, const float* __restrict__ AGG,
    const f16* __restrict__ Wf1T, const float* __restrict__ bf1,
    const f16* __restrict__ Wf2T, const float* __restrict__ bf2,
    const f16* __restrict__ Wf3T, const float* __restrict__ bf3,
    float* __restrict__ out)
{
    __shared__ __align__(16) f16 aug[64][328];
    __shared__ __align__(16) f16 p1[64][264];
    __shared__ __align__(16) f16 wl[256][72];
    int tid = threadIdx.x;
    int w = tid >> 6, lane = tid & 63, ln = lane & 15, q = lane >> 4;
    int m0 = blockIdx.x * 64;

    for (int it = 0; it < 10; ++it) {       // stage aug = [x | agg]
        int s = it*256 + tid;
        if (s < 512) {
            int m = s >> 3, hs = s & 7;
            int mrow = m0 + m;
            int b = mrow / 2016, r2 = mrow % 2016, t = r2 >> 5, n = r2 & 31;
            const float* px = &inputs[((b*NN + n)*NT + t)*ND + hs*8];
            f32x4 v0 = *(const f32x4*)px, v1 = *(const f32x4*)(px + 4);
            f16x8 o;
            #pragma unroll
            for (int e = 0; e < 4; ++e) { o[e] = (f16)v0[e]; o[e+4] = (f16)v1[e]; }
            *(f16x8*)&aug[m][hs*8] = o;
        } else {
            int s2 = s - 512;
            int m = s2 >> 5, hs = s2 & 31;
            const float* pa = &AGG[(size_t)(m0 + m)*NSO + hs*8];
            f32x4 v0 = *(const f32x4*)pa, v1 = *(const f32x4*)(pa + 4);
            f16x8 o;
            #pragma unroll
            for (int e = 0; e < 4; ++e) { o[e] = (f16)v0[e]; o[e+4] = (f16)v1[e]; }
            *(f16x8*)&aug[m][64 + hs*8] = o;
        }
    }
    const f32x4 z4 = {0.f, 0.f, 0.f, 0.f};
    // ---- layer 1: K=320 ----
    f32x4 acc1[16];
    #pragma unroll
    for (int nt = 0; nt < 16; ++nt) acc1[nt] = z4;
    for (int hc = 0; hc < 5; ++hc) {
        __syncthreads();
        #pragma unroll
        for (int it = 0; it < 8; ++it) {
            int idx8 = it*256 + tid;
            int co = idx8 >> 3, seg = idx8 & 7;
            *(f16x8*)&wl[co][seg*8] = *(const f16x8*)&Wf1T[co*320 + hc*64 + seg*8];
        }
        __syncthreads();
        #pragma unroll
        for (int ks = 0; ks < 2; ++ks) {
            f16x8 Af = *(const f16x8*)&aug[w*16 + ln][hc*64 + ks*32 + q*8];
            #pragma unroll
            for (int nt = 0; nt < 16; ++nt) {
                f16x8 Bf = *(const f16x8*)&wl[nt*16 + ln][ks*32 + q*8];
                acc1[nt] = __builtin_amdgcn_mfma_f32_16x16x32_f16(Af, Bf, acc1[nt], 0, 0, 0);
            }
        }
    }
    #pragma unroll
    for (int nt = 0; nt < 16; ++nt) {
        int co = nt*16 + ln;
        float bias = bf1[co];
        #pragma unroll
        for (int r = 0; r < 4; ++r) {
            float v = acc1[nt][r] + bias; v = v > 0.f ? v : 0.f;
            p1[w*16 + q*4 + r][co] = (f16)v;
        }
    }
    // ---- layer 2: K=256 ----
    f32x4 acc2[16];
    #pragma unroll
    for (int nt = 0; nt < 16; ++nt) acc2[nt] = z4;
    for (int hc = 0; hc < 4; ++hc) {
        __syncthreads();
        #pragma unroll
        for (int it = 0; it < 8; ++it) {
            int idx8 = it*256 + tid;
            int co = idx8 >> 3, seg = idx8 & 7;
            *(f16x8*)&wl[co][seg*8] = *(const f16x8*)&Wf2T[co*256 + hc*64 + seg*8];
        }
        __syncthreads();
        #pragma unroll
        for (int ks = 0; ks < 2; ++ks) {
            f16x8 Af = *(const f16x8*)&p1[w*16 + ln][hc*64 + ks*32 + q*8];
            #pragma unroll
            for (int nt = 0; nt < 16; ++nt) {
                f16x8 Bf = *(const f16x8*)&wl[nt*16 + ln][ks*32 + q*8];
                acc2[nt] = __builtin_amdgcn_mfma_f32_16x16x32_f16(Af, Bf, acc2[nt], 0, 0, 0);
            }
        }
    }
    f16* p2 = &aug[0][0];    // reuse aug storage, stride 264
    #pragma unroll
    for (int nt = 0; nt < 16; ++nt) {
        int co = nt*16 + ln;
        float bias = bf2[co];
        #pragma unroll
        for (int r = 0; r < 4; ++r) {
            float v = acc2[nt][r] + bias; v = v > 0.f ? v : 0.f;
            p2[(w*16 + q*4 + r)*264 + co] = (f16)v;
        }
    }
    __syncthreads();
    // ---- layer 3: K=256, N=64 ----
    f16* w3 = &wl[0][0];
    #pragma unroll
    for (int it = 0; it < 8; ++it) {
        int idx8 = it*256 + tid;
        int d = idx8 >> 5, seg = idx8 & 31;
        *(f16x8*)&w3[d*264 + seg*8] = *(const f16x8*)&Wf3T[d*256 + seg*8];
    }
    __syncthreads();
    f32x4 acc3[4];
    #pragma unroll
    for (int nt = 0; nt < 4; ++nt) acc3[nt] = z4;
    #pragma unroll
    for (int ks = 0; ks < 8; ++ks) {
        f16x8 Af = *(const f16x8*)&p2[(w*16 + ln)*264 + ks*32 + q*8];
        #pragma unroll
        for (int nt = 0; nt < 4; ++nt) {
            f16x8 Bf = *(const f16x8*)&w3[(nt*16 + ln)*264 + ks*32 + q*8];
            acc3[nt] = __builtin_amdgcn_mfma_f32_16x16x32_f16(Af, Bf, acc3[nt], 0, 0, 0);
        }
    }
    #pragma unroll
    for (int nt = 0; nt < 4; ++nt) {
        int d = nt*16 + ln;
        float bias = bf3[d];
        #pragma unroll
        for (int r = 0; r < 4; ++r) {
            int mrow = m0 + w*16 + q*4 + r;
            int b = mrow / 2016, r2 = mrow % 2016, t = r2 >> 5, n = r2 & 31;
            float xv = inputs[((b*NN + n)*NT + t)*ND + d];
            out[((size_t)(b*NN + n)*TOUT + t)*ND + d] = acc3[nt][r] + bias + xv;
        }
    }
}

extern "C" void kernel_launch(void* const* d_in, const int* in_sizes, int n_in,
                              void* d_out, int out_size, void* d_ws, size_t ws_size,
                              hipStream_t stream)
{
    const float* inputs = (const float*)d_in[0];
    const float* rel    = (const float*)d_in[1];
    const float* W1     = (const float*)d_in[4];
    const float* b1     = (const float*)d_in[5];
    const float* W2     = (const float*)d_in[6];
    const float* b2     = (const float*)d_in[7];
    const float* Wf1    = (const float*)d_in[8];
    const float* bf1    = (const float*)d_in[9];
    const float* Wf2    = (const float*)d_in[10];
    const float* bf2    = (const float*)d_in[11];
    const float* Wf3    = (const float*)d_in[12];
    const float* bf3    = (const float*)d_in[13];
    char* ws = (char*)d_ws;
    f16*   Rb   = (f16*)(ws + OFF_R);
    f16*   Sb   = (f16*)(ws + OFF_S);
    f16*   W2T  = (f16*)(ws + OFF_W2T);
    f16*   Wf1T = (f16*)(ws + OFF_WF1);
    f16*   Wf2T = (f16*)(ws + OFF_WF2);
    f16*   Wf3T = (f16*)(ws + OFF_WF3);
    float* REL  = (float*)(ws + OFF_REL);
    float* AGG  = (float*)(ws + OFF_AGG);
    f16*   W1T  = (f16*)(ws + OFF_W1T);
    float* out  = (float*)d_out;

    hipLaunchKernelGGL(k0_prep, dim3(2304), dim3(256), 0, stream,
                       W1, W2, Wf1, Wf2, Wf3, rel, W1T, W2T, Wf1T, Wf2T, Wf3T, REL,
                       (unsigned int*)AGG);
    hipLaunchKernelGGL(k1_partials, dim3(252), dim3(256), 0, stream,
                       inputs, W1T, b1, Rb, Sb);
    hipLaunchKernelGGL(k2_edge, dim3(1008), dim3(256), 0, stream,
                       Rb, Sb, W2T, b2, REL, AGG);
    hipLaunchKernelGGL(k3_node, dim3(252), dim3(256), 0, stream,
                       inputs, AGG, Wf1T, bf1, Wf2T, bf2, Wf3T, bf3, out);
}

// Round 11
// 475.867 us; speedup vs baseline: 1.1749x; 1.1547x over previous
//
#include <hip/hip_runtime.h>
#include <hip/hip_fp16.h>

typedef _Float16 f16;
typedef _Float16 f16x8 __attribute__((ext_vector_type(8)));
typedef _Float16 f16x4 __attribute__((ext_vector_type(4)));
typedef float    f32x4 __attribute__((ext_vector_type(4)));

#define AS1 __attribute__((address_space(1)))
#define AS3 __attribute__((address_space(3)))

// async 16B global->LDS DMA: LDS dest is wave-uniform base + lane*16.
__device__ __forceinline__ void gl_lds16(const void* g, void* l) {
    __builtin_amdgcn_global_load_lds((const AS1 unsigned int*)g,
                                     (AS3 unsigned int*)l, 16, 0, 0);
}

#define NB   8
#define NN   32
#define NT   64
#define ND   64
#define NK   4
#define NH   256
#define NSO  256
#define NE   992
#define TOUT 63
#define M1   (NB*TOUT*NN)   // 16128 node-time rows
#define NBT  (NB*TOUT)      // 504 (b,t) pairs

// ---- workspace layout (bytes) ----
static constexpr size_t SZ_RS   = (size_t)M1 * 1024 * 2;        // 33,030,144
static constexpr size_t OFF_R   = 0;
static constexpr size_t OFF_S   = OFF_R + SZ_RS;
static constexpr size_t OFF_W2T = OFF_S + SZ_RS;                // f16 [k][co][h] 524,288
static constexpr size_t OFF_WF1 = OFF_W2T + 4*256*256*2;        // f16 [co][d(320)]
static constexpr size_t OFF_WF2 = OFF_WF1 + 256*320*2;
static constexpr size_t OFF_WF3 = OFF_WF2 + 256*256*2;
static constexpr size_t OFF_REL = OFF_WF3 + 64*256*2;           // f32 [b][ns][k][32]
static constexpr size_t OFF_AGG = OFF_REL + (size_t)NB*NN*NK*32*4; // f32 [m][256] 16,515,072
static constexpr size_t OFF_W1T = OFF_AGG + (size_t)M1*256*4;   // f16 [c(2048)][d(64)]
// total = OFF_W1T + 262,144 = 83,820,544 bytes

// ============================ K0: weight prep + AGG zero ============================
__global__ __launch_bounds__(256) void k0_prep(
    const float* __restrict__ W1, const float* __restrict__ W2,
    const float* __restrict__ Wf1, const float* __restrict__ Wf2,
    const float* __restrict__ Wf3, const float* __restrict__ rel,
    f16* __restrict__ W1T, f16* __restrict__ W2T, f16* __restrict__ Wf1T,
    f16* __restrict__ Wf2T, f16* __restrict__ Wf3T, float* __restrict__ REL,
    unsigned int* __restrict__ AGGZ)
{
    int id = blockIdx.x * 256 + threadIdx.x;
    if (id < 262144) {                      // W2T[k][co][h] = W2[k][h][co]
        int k = id >> 16, co = (id >> 8) & 255, h = id & 255;
        W2T[id] = (f16)W2[k*65536 + h*256 + co];
    } else if (id < 344064) {               // Wf1T[co][d] = Wf1[d][co], d<320
        int i = id - 262144; int co = i / 320, d = i % 320;
        Wf1T[i] = (f16)Wf1[d*256 + co];
    } else if (id < 409600) {               // Wf2T[co][h] = Wf2[h][co]
        int i = id - 344064; int co = i >> 8, h = i & 255;
        Wf2T[i] = (f16)Wf2[h*256 + co];
    } else if (id < 425984) {               // Wf3T[d][h] = Wf3[h][d], d<64
        int i = id - 409600; int d = i >> 8, h = i & 255;
        Wf3T[i] = (f16)Wf3[h*64 + d];
    } else if (id < 458752) {               // REL[b][ns][k][j], self-edge -> 0
        int i = id - 425984;
        int j = i & 31, k = (i >> 5) & 3, ns = (i >> 7) & 31, b = i >> 12;
        float v = 0.f;
        if (j != ns) v = rel[(b*NE + ns*31 + (j < ns ? j : j - 1))*NK + k];
        REL[i] = v;
    } else {                                // W1T[c][d] = W1[k][dd*64+d][h] (131072 elems)
        int i = id - 458752;
        int c = i >> 6, d = i & 63;
        int k = c >> 9, dd = (c >> 8) & 1, h = c & 255;
        W1T[i] = (f16)W1[(k*128 + dd*64 + d)*NH + h];
    }
    // zero AGG (f32): 4,128,768 dwords = 7 x 589,824 threads exactly
    #pragma unroll
    for (int j = 0; j < 7; ++j) {
        int idx = id + j*589824;
        if (idx < 4128768) AGGZ[idx] = 0u;
    }
}

// ============ K1: per-node layer-1 partials R,S (MFMA, f16) ============
// Rb rows stored with each 64-f16 sub-block's 16B chunks swizzled by n&7
// (n = node = m&31) so k2's R LDS reads at chunk^(row&7) are conflict-free.
// Sb stored UNSWIZZLED: k2's S reads are lane-broadcast (row uniform), so no
// conflict concern, and plain layout gives base+const-offset addressing.
__global__ __launch_bounds__(256) void k1_partials(
    const float* __restrict__ inputs, const f16* __restrict__ W1T,
    const float* __restrict__ b1, f16* __restrict__ Rb, f16* __restrict__ Sb)
{
    __shared__ __align__(16) f16 xs[64][72];
    __shared__ __align__(16) f16 wl[256][72];
    int tid = threadIdx.x;
    int w = tid >> 6, lane = tid & 63, ln = lane & 15, q = lane >> 4;
    int m0 = blockIdx.x * 64;

    #pragma unroll
    for (int it = 0; it < 2; ++it) {             // stage x -> f16
        int idx8 = it*256 + tid;
        int m = idx8 >> 3, hs = idx8 & 7;
        int mrow = m0 + m;
        int b = mrow / 2016, r2 = mrow % 2016, t = r2 >> 5, n = r2 & 31;
        const float* px = &inputs[((b*NN + n)*NT + t)*ND + hs*8];
        f32x4 v0 = *(const f32x4*)px, v1 = *(const f32x4*)(px + 4);
        f16x8 o;
        #pragma unroll
        for (int e = 0; e < 4; ++e) { o[e] = (f16)v0[e]; o[e+4] = (f16)v1[e]; }
        *(f16x8*)&xs[m][hs*8] = o;
    }
    const f32x4 z4 = {0.f, 0.f, 0.f, 0.f};
    for (int cc = 0; cc < 8; ++cc) {             // 8 chunks of 256 output cols
        int k = cc >> 1, dd = cc & 1;
        __syncthreads();
        #pragma unroll
        for (int it = 0; it < 8; ++it) {
            int idx8 = it*256 + tid;
            int co = idx8 >> 3, seg = idx8 & 7;
            *(f16x8*)&wl[co][seg*8] = *(const f16x8*)&W1T[(size_t)(cc*256 + co)*64 + seg*8];
        }
        __syncthreads();
        f32x4 acc[16];
        #pragma unroll
        for (int nt = 0; nt < 16; ++nt) acc[nt] = z4;
        #pragma unroll
        for (int ks = 0; ks < 2; ++ks) {
            f16x8 Af = *(const f16x8*)&xs[w*16 + ln][ks*32 + q*8];
            #pragma unroll
            for (int nt = 0; nt < 16; ++nt) {
                f16x8 Bf = *(const f16x8*)&wl[nt*16 + ln][ks*32 + q*8];
                acc[nt] = __builtin_amdgcn_mfma_f32_16x16x32_f16(Af, Bf, acc[nt], 0, 0, 0);
            }
        }
        __syncthreads();
        f16* ob = &wl[0][0];                      // out-stage, stride 264
        #pragma unroll
        for (int nt = 0; nt < 16; ++nt) {
            int co = nt*16 + ln;
            float bias = dd ? b1[k*NH + co] : 0.f;
            #pragma unroll
            for (int r = 0; r < 4; ++r) {
                float v = acc[nt][r] + bias;
                ob[(w*16 + q*4 + r)*264 + co] = (f16)v;
            }
        }
        __syncthreads();
        f16* dst = dd ? Sb : Rb;
        #pragma unroll
        for (int it = 0; it < 8; ++it) {          // coalesced stores
            int idx8 = it*256 + tid;
            int m = idx8 >> 5, seg = idx8 & 31;
            int hcb = seg >> 3, c = seg & 7;
            int cs = dd ? c : (c ^ (m & 7));      // Rb swizzled, Sb plain
            *(f16x8*)&dst[(size_t)(m0 + m)*1024 + k*256 + hcb*64 + c*8] =
                *(const f16x8*)&ob[m*264 + hcb*64 + (cs << 3)];
        }
    }
}

// ============ K2: edge MLP layer-2, W2 in REGISTERS ============
// Block = (k, bt-chunk of 4): grid 504, 256 thr (4 waves = 4 ng), 2 blocks/CU.
// Tile = (bt, nsp): 2 senders x 32 receivers (M=64), 16 nsp per bt.
// Per lane: Breg 128 + acc 64 -> 2 waves/SIMD is structural (r10: shrinking
// Breg via co-split duplicates A-build VALU device-wide and regresses; K-split
// is illegal -- epilogue relu needs complete K=256 pre-activation).
// S ring of 4 slots, prefetch distance 2 -> __syncthreads every 2 tiles (32
// barriers, was 64). Per-tile DMA cadence proven (r9: per-ibt bursts serialize
// on the barrier's vmcnt(0) drain). Bias folded into acc init.
// NEVER cap regs below Breg+acc+misc (r3: (512,6) spilled, 4x regression).
__global__ __launch_bounds__(256, 2) void k2_edge(
    const f16* __restrict__ Rb, const f16* __restrict__ Sb,
    const f16* __restrict__ W2T, const float* __restrict__ b2,
    const float* __restrict__ REL, float* __restrict__ AGG)
{
    __shared__ __align__(16) f16 Rbuf[2][32*256];   // 16 KB per buf
    __shared__ __align__(16) f16 Sbuf[4][2*256];    // 1 KB per slot
    int tid = threadIdx.x;
    int blk = blockIdx.x;
    int k = blk & 3, g = blk >> 2;               // g in 0..125 -> bt = g*4..g*4+3
    int ng = tid >> 6, lane = tid & 63, ln = lane & 15, q = lane >> 4;
    int lrow = lane >> 5, lseg = lane & 31;      // DMA: 2 rows x 32 chunks per call

    // ---- W2(k) fragments in registers + bias ----
    f16x8 Breg[4][8];
    f32x4 bini[4];
    #pragma unroll
    for (int nt = 0; nt < 4; ++nt) {
        int co = ng*64 + nt*16 + ln;
        float bv = b2[k*256 + co];
        f32x4 bb = {bv, bv, bv, bv};
        bini[nt] = bb;
        const f16* wrow = &W2T[(size_t)(k*256 + co)*256];
        #pragma unroll
        for (int ks = 0; ks < 8; ++ks)
            Breg[nt][ks] = *(const f16x8*)&wrow[ks*32 + q*8];
    }

    auto stageR = [&](int bt, int buf) {         // 16 KB: 4 calls/wave x 4 waves
        #pragma unroll
        for (int it = 0; it < 4; ++it) {
            int rowbase = ng*8 + it*2;
            gl_lds16(&Rb[((size_t)bt*NN + rowbase + lrow)*1024 + k*256 + lseg*8],
                     &Rbuf[buf][rowbase*256 + lane*8]);
        }
    };
    auto stageS = [&](int i, int slot) {         // 1 KB: 1 call (wave 0)
        int bt = g*4 + (i >> 4), nsp = i & 15;
        if (ng == 0)
            gl_lds16(&Sb[((size_t)bt*NN + nsp*2 + lrow)*1024 + k*256 + lseg*8],
                     &Sbuf[slot][lane*8]);
    };

    stageR(g*4, 0);
    stageS(0, 0);
    stageS(1, 1);
    __syncthreads();

    const f16x8 zf = {0,0,0,0,0,0,0,0};
    for (int i = 0; i < 64; ++i) {
        int ibt = i >> 4, nsp = i & 15;
        int bt = g*4 + ibt, b = bt / TOUT;
        int rb = ibt & 1;
        if (i < 62) stageS(i + 2, (i + 2) & 3);  // slot reused 4 tiles later
        if (nsp == 14 && ibt < 3) stageR(bt + 1, rb ^ 1);

        const f16* Rl = &Rbuf[rb][0];
        const f16* Sl = &Sbuf[i & 3][0];
        int ns0 = nsp*2;                         // senders ns0, ns0+1
        f32x4 acc[4][4];
        #pragma unroll
        for (int mt = 0; mt < 4; ++mt)
            #pragma unroll
            for (int nt = 0; nt < 4; ++nt) acc[mt][nt] = bini[nt];

        #pragma unroll
        for (int ks = 0; ks < 8; ++ks) {
            int hc = ks >> 1;
            int c4 = (ks & 1)*4 + q;
            int paR = hc*64 + ((c4 ^ (ln & 7)) << 3);
            int paS = hc*64 + c4*8;              // Sb unswizzled: base + const
            f16x8 rlo = *(const f16x8*)&Rl[ln*256 + paR];
            f16x8 rhi = *(const f16x8*)&Rl[(16 + ln)*256 + paR];
            f16x8 s0 = *(const f16x8*)&Sl[0*256 + paS];
            f16x8 s1 = *(const f16x8*)&Sl[1*256 + paS];
            f16x8 A[4];
            A[0] = __builtin_elementwise_max(rlo + s0, zf);   // sender0, rows 0-15
            A[1] = __builtin_elementwise_max(rhi + s0, zf);   // sender0, rows 16-31
            A[2] = __builtin_elementwise_max(rlo + s1, zf);   // sender1, rows 0-15
            A[3] = __builtin_elementwise_max(rhi + s1, zf);   // sender1, rows 16-31
            #pragma unroll
            for (int nt = 0; nt < 4; ++nt) {
                f16x8 Bf = Breg[nt][ks];
                #pragma unroll
                for (int mt = 0; mt < 4; ++mt)
                    acc[mt][nt] = __builtin_amdgcn_mfma_f32_16x16x32_f16(
                        A[mt], Bf, acc[mt][nt], 0, 0, 0);
            }
        }
        // epilogue: relu (bias in acc), rel-weight, reduce over 32 j, atomic
        #pragma unroll
        for (int half = 0; half < 2; ++half) {
            int ns = ns0 + half;
            const float* relp = &REL[(((size_t)b*NN + ns)*NK + k)*32];
            f32x4 rel0 = *(const f32x4*)&relp[q*4];
            f32x4 rel1 = *(const f32x4*)&relp[16 + q*4];
            #pragma unroll
            for (int nt = 0; nt < 4; ++nt) {
                float s = 0.f;
                #pragma unroll
                for (int r = 0; r < 4; ++r) {
                    float v0 = acc[2*half + 0][nt][r];
                    float v1 = acc[2*half + 1][nt][r];
                    v0 = v0 > 0.f ? v0 : 0.f;
                    v1 = v1 > 0.f ? v1 : 0.f;
                    s += v0 * rel0[r] + v1 * rel1[r];
                }
                s += __shfl_xor(s, 16);
                s += __shfl_xor(s, 32);
                if (lane < 16)
                    atomicAdd(&AGG[((size_t)bt*NN + ns)*256 + ng*64 + nt*16 + lane], s);
            }
        }
        if (i & 1) __syncthreads();              // every 2 tiles: protects S-slot
    }                                            // reuse (+4) and R-buf reuse
}

// ============ K3: node MLP (320->256->256->64) + residual ============
__global__ __launch_bounds__(256) void k3_node(
    const float* __restrict__ inputs, const float* __restrict__ AGG,
    const f16* __restrict__ Wf1T, const float* __restrict__ bf1,
    const f16* __restrict__ Wf2T, const float* __restrict__ bf2,
    const f16* __restrict__ Wf3T, const float* __restrict__ bf3,
    float* __restrict__ out)
{
    __shared__ __align__(16) f16 aug[64][328];
    __shared__ __align__(16) f16 p1[64][264];
    __shared__ __align__(16) f16 wl[256][72];
    int tid = threadIdx.x;
    int w = tid >> 6, lane = tid & 63, ln = lane & 15, q = lane >> 4;
    int m0 = blockIdx.x * 64;

    for (int it = 0; it < 10; ++it) {       // stage aug = [x | agg]
        int s = it*256 + tid;
        if (s < 512) {
            int m = s >> 3, hs = s & 7;
            int mrow = m0 + m;
            int b = mrow / 2016, r2 = mrow % 2016, t = r2 >> 5, n = r2 & 31;
            const float* px = &inputs[((b*NN + n)*NT + t)*ND + hs*8];
            f32x4 v0 = *(const f32x4*)px, v1 = *(const f32x4*)(px + 4);
            f16x8 o;
            #pragma unroll
            for (int e = 0; e < 4; ++e) { o[e] = (f16)v0[e]; o[e+4] = (f16)v1[e]; }
            *(f16x8*)&aug[m][hs*8] = o;
        } else {
            int s2 = s - 512;
            int m = s2 >> 5, hs = s2 & 31;
            const float* pa = &AGG[(size_t)(m0 + m)*NSO + hs*8];
            f32x4 v0 = *(const f32x4*)pa, v1 = *(const f32x4*)(pa + 4);
            f16x8 o;
            #pragma unroll
            for (int e = 0; e < 4; ++e) { o[e] = (f16)v0[e]; o[e+4] = (f16)v1[e]; }
            *(f16x8*)&aug[m][64 + hs*8] = o;
        }
    }
    const f32x4 z4 = {0.f, 0.f, 0.f, 0.f};
    // ---- layer 1: K=320 ----
    f32x4 acc1[16];
    #pragma unroll
    for (int nt = 0; nt < 16; ++nt) acc1[nt] = z4;
    for (int hc = 0; hc < 5; ++hc) {
        __syncthreads();
        #pragma unroll
        for (int it = 0; it < 8; ++it) {
            int idx8 = it*256 + tid;
            int co = idx8 >> 3, seg = idx8 & 7;
            *(f16x8*)&wl[co][seg*8] = *(const f16x8*)&Wf1T[co*320 + hc*64 + seg*8];
        }
        __syncthreads();
        #pragma unroll
        for (int ks = 0; ks < 2; ++ks) {
            f16x8 Af = *(const f16x8*)&aug[w*16 + ln][hc*64 + ks*32 + q*8];
            #pragma unroll
            for (int nt = 0; nt < 16; ++nt) {
                f16x8 Bf = *(const f16x8*)&wl[nt*16 + ln][ks*32 + q*8];
                acc1[nt] = __builtin_amdgcn_mfma_f32_16x16x32_f16(Af, Bf, acc1[nt], 0, 0, 0);
            }
        }
    }
    #pragma unroll
    for (int nt = 0; nt < 16; ++nt) {
        int co = nt*16 + ln;
        float bias = bf1[co];
        #pragma unroll
        for (int r = 0; r < 4; ++r) {
            float v = acc1[nt][r] + bias; v = v > 0.f ? v : 0.f;
            p1[w*16 + q*4 + r][co] = (f16)v;
        }
    }
    // ---- layer 2: K=256 ----
    f32x4 acc2[16];
    #pragma unroll
    for (int nt = 0; nt < 16; ++nt) acc2[nt] = z4;
    for (int hc = 0; hc < 4; ++hc) {
        __syncthreads();
        #pragma unroll
        for (int it = 0; it < 8; ++it) {
            int idx8 = it*256 + tid;
            int co = idx8 >> 3, seg = idx8 & 7;
            *(f16x8*)&wl[co][seg*8] = *(const f16x8*)&Wf2T[co*256 + hc*64 + seg*8];
        }
        __syncthreads();
        #pragma unroll
        for (int ks = 0; ks < 2; ++ks) {
            f16x8 Af = *(const f16x8*)&p1[w*16 + ln][hc*64 + ks*32 + q*8];
            #pragma unroll
            for (int nt = 0; nt < 16; ++nt) {
                f16x8 Bf = *(const f16x8*)&wl[nt*16 + ln][ks*32 + q*8];
                acc2[nt] = __builtin_amdgcn_mfma_f32_16x16x32_f16(Af, Bf, acc2[nt], 0, 0, 0);
            }
        }
    }
    f16* p2 = &aug[0][0];    // reuse aug storage, stride 264
    #pragma unroll
    for (int nt = 0; nt < 16; ++nt) {
        int co = nt*16 + ln;
        float bias = bf2[co];
        #pragma unroll
        for (int r = 0; r < 4; ++r) {
            float v = acc2[nt][r] + bias; v = v > 0.f ? v : 0.f;
            p2[(w*16 + q*4 + r)*264 + co] = (f16)v;
        }
    }
    __syncthreads();
    // ---- layer 3: K=256, N=64 ----
    f16* w3 = &wl[0][0];
    #pragma unroll
    for (int it = 0; it < 8; ++it) {
        int idx8 = it*256 + tid;
        int d = idx8 >> 5, seg = idx8 & 31;
        *(f16x8*)&w3[d*264 + seg*8] = *(const f16x8*)&Wf3T[d*256 + seg*8];
    }
    __syncthreads();
    f32x4 acc3[4];
    #pragma unroll
    for (int nt = 0; nt < 4; ++nt) acc3[nt] = z4;
    #pragma unroll
    for (int ks = 0; ks < 8; ++ks) {
        f16x8 Af = *(const f16x8*)&p2[(w*16 + ln)*264 + ks*32 + q*8];
        #pragma unroll
        for (int nt = 0; nt < 4; ++nt) {
            f16x8 Bf = *(const f16x8*)&w3[(nt*16 + ln)*264 + ks*32 + q*8];
            acc3[nt] = __builtin_amdgcn_mfma_f32_16x16x32_f16(Af, Bf, acc3[nt], 0, 0, 0);
        }
    }
    #pragma unroll
    for (int nt = 0; nt < 4; ++nt) {
        int d = nt*16 + ln;
        float bias = bf3[d];
        #pragma unroll
        for (int r = 0; r < 4; ++r) {
            int mrow = m0 + w*16 + q*4 + r;
            int b = mrow / 2016, r2 = mrow % 2016, t = r2 >> 5, n = r2 & 31;
            float xv = inputs[((b*NN + n)*NT + t)*ND + d];
            out[((size_t)(b*NN + n)*TOUT + t)*ND + d] = acc3[nt][r] + bias + xv;
        }
    }
}

extern "C" void kernel_launch(void* const* d_in, const int* in_sizes, int n_in,
                              void* d_out, int out_size, void* d_ws, size_t ws_size,
                              hipStream_t stream)
{
    const float* inputs = (const float*)d_in[0];
    const float* rel    = (const float*)d_in[1];
    const float* W1     = (const float*)d_in[4];
    const float* b1     = (const float*)d_in[5];
    const float* W2     = (const float*)d_in[6];
    const float* b2     = (const float*)d_in[7];
    const float* Wf1    = (const float*)d_in[8];
    const float* bf1    = (const float*)d_in[9];
    const float* Wf2    = (const float*)d_in[10];
    const float* bf2    = (const float*)d_in[11];
    const float* Wf3    = (const float*)d_in[12];
    const float* bf3    = (const float*)d_in[13];
    char* ws = (char*)d_ws;
    f16*   Rb   = (f16*)(ws + OFF_R);
    f16*   Sb   = (f16*)(ws + OFF_S);
    f16*   W2T  = (f16*)(ws + OFF_W2T);
    f16*   Wf1T = (f16*)(ws + OFF_WF1);
    f16*   Wf2T = (f16*)(ws + OFF_WF2);
    f16*   Wf3T = (f16*)(ws + OFF_WF3);
    float* REL  = (float*)(ws + OFF_REL);
    float* AGG  = (float*)(ws + OFF_AGG);
    f16*   W1T  = (f16*)(ws + OFF_W1T);
    float* out  = (float*)d_out;

    hipLaunchKernelGGL(k0_prep, dim3(2304), dim3(256), 0, stream,
                       W1, W2, Wf1, Wf2, Wf3, rel, W1T, W2T, Wf1T, Wf2T, Wf3T, REL,
                       (unsigned int*)AGG);
    hipLaunchKernelGGL(k1_partials, dim3(252), dim3(256), 0, stream,
                       inputs, W1T, b1, Rb, Sb);
    hipLaunchKernelGGL(k2_edge, dim3(504), dim3(256), 0, stream,
                       Rb, Sb, W2T, b2, REL, AGG);
    hipLaunchKernelGGL(k3_node, dim3(252), dim3(256), 0, stream,
                       inputs, AGG, Wf1T, bf1, Wf2T, bf2, Wf3T, bf3, out);
}

// Round 12
// 450.423 us; speedup vs baseline: 1.2413x; 1.0565x over previous
//
#include <hip/hip_runtime.h>
#include <hip/hip_fp16.h>

typedef _Float16 f16;
typedef _Float16 f16x8 __attribute__((ext_vector_type(8)));
typedef _Float16 f16x4 __attribute__((ext_vector_type(4)));
typedef float    f32x4 __attribute__((ext_vector_type(4)));

#define AS1 __attribute__((address_space(1)))
#define AS3 __attribute__((address_space(3)))

// async 16B global->LDS DMA: LDS dest is wave-uniform base + lane*16.
__device__ __forceinline__ void gl_lds16(const void* g, void* l) {
    __builtin_amdgcn_global_load_lds((const AS1 unsigned int*)g,
                                     (AS3 unsigned int*)l, 16, 0, 0);
}

#define NB   8
#define NN   32
#define NT   64
#define ND   64
#define NK   4
#define NH   256
#define NSO  256
#define NE   992
#define TOUT 63
#define M1   (NB*TOUT*NN)   // 16128 node-time rows
#define NBT  (NB*TOUT)      // 504 (b,t) pairs

// ---- workspace layout (bytes) ----
static constexpr size_t SZ_RS   = (size_t)M1 * 1024 * 2;        // 33,030,144
static constexpr size_t OFF_R   = 0;
static constexpr size_t OFF_S   = OFF_R + SZ_RS;
static constexpr size_t OFF_W2T = OFF_S + SZ_RS;                // f16 [k][co][h] plain
static constexpr size_t OFF_WF1 = OFF_W2T + 4*256*256*2;        // f16 [co][320] swizzled
static constexpr size_t OFF_WF2 = OFF_WF1 + 256*320*2;          // f16 [co][256] swizzled
static constexpr size_t OFF_WF3 = OFF_WF2 + 256*256*2;          // f16 [d][256] swizzled
static constexpr size_t OFF_REL = OFF_WF3 + 64*256*2;           // f32 [b][ns][k][32]
static constexpr size_t OFF_AGG = OFF_REL + (size_t)NB*NN*NK*32*4; // f32 [m][256]
static constexpr size_t OFF_W1T = OFF_AGG + (size_t)M1*256*4;   // f16 [c(2048)][64] swizzled
// total = OFF_W1T + 262,144 = 83,820,544 bytes

// ============================ K0: weight prep + AGG zero ============================
// W1TS/Wf1TS/Wf2TS: 16B chunks of each 64-col sub-row pre-swizzled by (row&7);
// Wf3TS: 32 chunks, low-3 bits swizzled by (d&7). Linear DMA staging in k1/k3
// then reads at chunk^(ln&7) conflict-free (m136: 2-way is free).
__global__ __launch_bounds__(256) void k0_prep(
    const float* __restrict__ W1, const float* __restrict__ W2,
    const float* __restrict__ Wf1, const float* __restrict__ Wf2,
    const float* __restrict__ Wf3, const float* __restrict__ rel,
    f16* __restrict__ W1TS, f16* __restrict__ W2T, f16* __restrict__ Wf1TS,
    f16* __restrict__ Wf2TS, f16* __restrict__ Wf3TS, float* __restrict__ REL,
    unsigned int* __restrict__ AGGZ)
{
    int id = blockIdx.x * 256 + threadIdx.x;
    if (id < 262144) {                      // W2T[k][co][h] = W2[k][h][co] (plain)
        int k = id >> 16, co = (id >> 8) & 255, h = id & 255;
        W2T[id] = (f16)W2[k*65536 + h*256 + co];
    } else if (id < 344064) {               // Wf1TS[co][dcol], d<320, swizzled
        int i = id - 262144; int co = i / 320, dcol = i % 320;
        int hc = dcol >> 6, c8 = (dcol >> 3) & 7, e = dcol & 7;
        int sd = hc*64 + ((c8 ^ (co & 7)) << 3) + e;
        Wf1TS[i] = (f16)Wf1[sd*256 + co];
    } else if (id < 409600) {               // Wf2TS[co][h], swizzled
        int i = id - 344064; int co = i >> 8, dcol = i & 255;
        int hc = dcol >> 6, c8 = (dcol >> 3) & 7, e = dcol & 7;
        int sh = hc*64 + ((c8 ^ (co & 7)) << 3) + e;
        Wf2TS[i] = (f16)Wf2[sh*256 + co];
    } else if (id < 425984) {               // Wf3TS[d][col], swizzled (32 chunks)
        int i = id - 409600; int d = i >> 8, col = i & 255;
        int c32 = col >> 3, e = col & 7;
        int sc = (c32 & 24) | ((c32 & 7) ^ (d & 7));
        Wf3TS[i] = (f16)Wf3[(sc*8 + e)*64 + d];
    } else if (id < 458752) {               // REL[b][ns][k][j], self-edge -> 0
        int i = id - 425984;
        int j = i & 31, k = (i >> 5) & 3, ns = (i >> 7) & 31, b = i >> 12;
        float v = 0.f;
        if (j != ns) v = rel[(b*NE + ns*31 + (j < ns ? j : j - 1))*NK + k];
        REL[i] = v;
    } else {                                // W1TS[c][dcol], swizzled (131072 elems)
        int i = id - 458752;
        int c = i >> 6, dcol = i & 63;
        int c8 = (dcol >> 3) & 7, e = dcol & 7;
        int sd = ((c8 ^ (c & 7)) << 3) + e;
        int k = c >> 9, dd = (c >> 8) & 1, h = c & 255;
        W1TS[i] = (f16)W1[(k*128 + dd*64 + sd)*NH + h];
    }
    // zero AGG (f32): 4,128,768 dwords = 7 x 589,824 threads exactly
    #pragma unroll
    for (int j = 0; j < 7; ++j) {
        int idx = id + j*589824;
        if (idx < 4128768) AGGZ[idx] = 0u;
    }
}

// ============ K1: per-node layer-1 partials R,S (MFMA, f16, DMA dbuf) ============
// Rb/Sb rows stored with each 64-f16 sub-block's 16B chunks swizzled by n&7
// (n = node = m&31) so k2's LDS reads at chunk^(row&7) are conflict-free.
// W1TS staged via DMA double-buffer (pre-swizzled); 2 barriers/chunk (was 3 +
// VGPR round-trip). Grid 252 = 1 block/CU -> big LDS is free.
__global__ __launch_bounds__(256) void k1_partials(
    const float* __restrict__ inputs, const f16* __restrict__ W1TS,
    const float* __restrict__ b1, f16* __restrict__ Rb, f16* __restrict__ Sb)
{
    __shared__ __align__(16) f16 xs[64][72];      // A: 64 rows x 64 d (padded)
    __shared__ __align__(16) f16 wl[2][256*64];   // B dbuf (swizzled content)
    __shared__ __align__(16) f16 ob[64*264];      // out-stage
    int tid = threadIdx.x;
    int w = tid >> 6, lane = tid & 63, ln = lane & 15, q = lane >> 4;
    int lrow8 = lane >> 3, lc8 = lane & 7;
    int m0 = blockIdx.x * 64;

    #pragma unroll
    for (int it = 0; it < 2; ++it) {             // stage x -> f16
        int idx8 = it*256 + tid;
        int m = idx8 >> 3, hs = idx8 & 7;
        int mrow = m0 + m;
        int b = mrow / 2016, r2 = mrow % 2016, t = r2 >> 5, n = r2 & 31;
        const float* px = &inputs[((b*NN + n)*NT + t)*ND + hs*8];
        f32x4 v0 = *(const f32x4*)px, v1 = *(const f32x4*)(px + 4);
        f16x8 o;
        #pragma unroll
        for (int e = 0; e < 4; ++e) { o[e] = (f16)v0[e]; o[e+4] = (f16)v1[e]; }
        *(f16x8*)&xs[m][hs*8] = o;
    }
    auto stageW = [&](int cc, int buf) {         // 32 KB: 8 calls/wave
        #pragma unroll
        for (int it = 0; it < 8; ++it) {
            int co0 = (it*4 + w)*8;
            gl_lds16(&W1TS[(size_t)(cc*256 + co0 + lrow8)*64 + lc8*8],
                     &wl[buf][co0*64 + lane*8]);
        }
    };
    stageW(0, 0);
    __syncthreads();

    const f32x4 z4 = {0.f, 0.f, 0.f, 0.f};
    for (int cc = 0; cc < 8; ++cc) {             // 8 chunks of 256 output cols
        int k = cc >> 1, dd = cc & 1;
        if (cc < 7) stageW(cc + 1, (cc + 1) & 1);
        const f16* wb = &wl[cc & 1][0];
        f32x4 acc[16];
        #pragma unroll
        for (int nt = 0; nt < 16; ++nt) acc[nt] = z4;
        #pragma unroll
        for (int ks = 0; ks < 2; ++ks) {
            f16x8 Af = *(const f16x8*)&xs[w*16 + ln][ks*32 + q*8];
            #pragma unroll
            for (int nt = 0; nt < 16; ++nt) {
                f16x8 Bf = *(const f16x8*)&wb[(nt*16 + ln)*64 +
                                (((ks*4 + q) ^ (ln & 7)) << 3)];
                acc[nt] = __builtin_amdgcn_mfma_f32_16x16x32_f16(Af, Bf, acc[nt], 0, 0, 0);
            }
        }
        #pragma unroll
        for (int nt = 0; nt < 16; ++nt) {
            int co = nt*16 + ln;
            float bias = dd ? b1[k*NH + co] : 0.f;
            #pragma unroll
            for (int r = 0; r < 4; ++r) {
                float v = acc[nt][r] + bias;
                ob[(w*16 + q*4 + r)*264 + co] = (f16)v;
            }
        }
        __syncthreads();                          // ob ready; DMA(cc+1) drained
        f16* dst = dd ? Sb : Rb;
        #pragma unroll
        for (int it = 0; it < 8; ++it) {          // swizzled coalesced stores
            int idx8 = it*256 + tid;
            int m = idx8 >> 5, seg = idx8 & 31;
            int hcb = seg >> 3, c = seg & 7;
            *(f16x8*)&dst[(size_t)(m0 + m)*1024 + k*256 + hcb*64 + c*8] =
                *(const f16x8*)&ob[m*264 + hcb*64 + (((c ^ (m & 7))) << 3)];
        }
        __syncthreads();                          // ob reuse
    }
}

// ============ K2: edge MLP layer-2, W2 resident in REGISTERS ============
// ROUND-7 structure (best measured: 349 us) + bias folded into acc init.
// Block = (k, bt-chunk of 8): grid 252, 512 thr, 1 block/CU.
// Per lane: B-frags 4 col-tiles x K=256 = 128 VGPR, loaded once.
// LDS: R dbuf (2x16KB, reused by 8 nsq tiles) + S dbuf (2x2KB) via DMA.
// Plateau notes: r8-r11 variants (256-thr, co-split, barrier-halving, burst
// staging) all land 349-447 -- 2 waves/SIMD latency-bound is structural.
__global__ __launch_bounds__(512, 2) void k2_edge(
    const f16* __restrict__ Rb, const f16* __restrict__ Sb,
    const f16* __restrict__ W2T, const float* __restrict__ b2,
    const float* __restrict__ REL, float* __restrict__ AGG)
{
    __shared__ __align__(16) f16 Rbuf[2][32*256];
    __shared__ __align__(16) f16 Sbuf[2][4*256];
    int tid = threadIdx.x;
    int blk = blockIdx.x;
    int k = blk & 3, g = blk >> 2;               // g in 0..62 -> bt = g*8..g*8+7
    int w = tid >> 6, lane = tid & 63, ln = lane & 15, q = lane >> 4;
    int mg = w >> 2, ng = w & 3;
    int lrow = lane >> 5, lseg = lane & 31;      // DMA: 2 rows x 32 chunks per call

    // ---- W2(k) fragments in registers + bias (folded into acc init) ----
    f16x8 Breg[4][8];
    f32x4 bini[4];
    #pragma unroll
    for (int nt = 0; nt < 4; ++nt) {
        int co = ng*64 + nt*16 + ln;
        float bv = b2[k*256 + co];
        f32x4 bb = {bv, bv, bv, bv};
        bini[nt] = bb;
        const f16* wrow = &W2T[(size_t)(k*256 + co)*256];
        #pragma unroll
        for (int ks = 0; ks < 8; ++ks)
            Breg[nt][ks] = *(const f16x8*)&wrow[ks*32 + q*8];
    }

    auto stageR = [&](int bt, int buf) {         // 16 KB: 16 calls (2/wave)
        #pragma unroll
        for (int it = 0; it < 2; ++it) {
            int rowbase = (w*2 + it)*2;
            gl_lds16(&Rb[((size_t)bt*NN + rowbase + lrow)*1024 + k*256 + lseg*8],
                     &Rbuf[buf][rowbase*256 + lane*8]);
        }
    };
    auto stageS = [&](int i, int buf) {          // 2 KB: 2 calls (waves 0,1)
        int bt = g*8 + (i >> 3), nsq = i & 7;
        if (w < 2)
            gl_lds16(&Sb[((size_t)bt*NN + nsq*4 + w*2 + lrow)*1024 + k*256 + lseg*8],
                     &Sbuf[buf][(w*2)*256 + lane*8]);
    };

    stageR(g*8, 0);
    stageS(0, 0);
    __syncthreads();

    const f16x8 zf = {0,0,0,0,0,0,0,0};
    for (int i = 0; i < 64; ++i) {
        int ibt = i >> 3, nsq = i & 7;
        int bt = g*8 + ibt, b = bt / TOUT;
        int rb = ibt & 1, sb = i & 1;
        if (i < 63) stageS(i + 1, sb ^ 1);
        if (nsq == 6 && ibt < 7) stageR(bt + 1, rb ^ 1);

        const f16* Rl = &Rbuf[rb][0];
        const f16* Sl = &Sbuf[sb][0];
        int ns0 = nsq*4 + mg*2;                  // this wave's first sender
        f32x4 acc[4][4];
        #pragma unroll
        for (int mt = 0; mt < 4; ++mt)
            #pragma unroll
            for (int nt = 0; nt < 4; ++nt) acc[mt][nt] = bini[nt];

        #pragma unroll
        for (int ks = 0; ks < 8; ++ks) {
            int hc = ks >> 1;
            int c4 = (ks & 1)*4 + q;
            int paR = hc*64 + ((c4 ^ (ln & 7)) << 3);
            f16x8 rlo = *(const f16x8*)&Rl[ln*256 + paR];
            f16x8 rhi = *(const f16x8*)&Rl[(16 + ln)*256 + paR];
            f16x8 s0 = *(const f16x8*)&Sl[(mg*2 + 0)*256 + hc*64 + ((c4 ^ (ns0 & 7)) << 3)];
            f16x8 s1 = *(const f16x8*)&Sl[(mg*2 + 1)*256 + hc*64 + ((c4 ^ ((ns0 + 1) & 7)) << 3)];
            f16x8 A[4];
            A[0] = __builtin_elementwise_max(rlo + s0, zf);   // sender0, rows 0-15
            A[1] = __builtin_elementwise_max(rhi + s0, zf);   // sender0, rows 16-31
            A[2] = __builtin_elementwise_max(rlo + s1, zf);   // sender1, rows 0-15
            A[3] = __builtin_elementwise_max(rhi + s1, zf);   // sender1, rows 16-31
            #pragma unroll
            for (int nt = 0; nt < 4; ++nt) {
                f16x8 Bf = Breg[nt][ks];
                #pragma unroll
                for (int mt = 0; mt < 4; ++mt)
                    acc[mt][nt] = __builtin_amdgcn_mfma_f32_16x16x32_f16(
                        A[mt], Bf, acc[mt][nt], 0, 0, 0);
            }
        }
        // epilogue: relu (bias in acc), rel-weight, reduce over 32 j, atomic
        #pragma unroll
        for (int half = 0; half < 2; ++half) {
            int ns = ns0 + half;
            const float* relp = &REL[(((size_t)b*NN + ns)*NK + k)*32];
            f32x4 rel0 = *(const f32x4*)&relp[q*4];
            f32x4 rel1 = *(const f32x4*)&relp[16 + q*4];
            #pragma unroll
            for (int nt = 0; nt < 4; ++nt) {
                float s = 0.f;
                #pragma unroll
                for (int r = 0; r < 4; ++r) {
                    float v0 = acc[2*half + 0][nt][r];
                    float v1 = acc[2*half + 1][nt][r];
                    v0 = v0 > 0.f ? v0 : 0.f;
                    v1 = v1 > 0.f ? v1 : 0.f;
                    s += v0 * rel0[r] + v1 * rel1[r];
                }
                s += __shfl_xor(s, 16);
                s += __shfl_xor(s, 32);
                if (lane < 16)
                    atomicAdd(&AGG[((size_t)bt*NN + ns)*256 + ng*64 + nt*16 + lane], s);
            }
        }
        __syncthreads();
    }
}

// ============ K3: node MLP (320->256->256->64) + residual, DMA dbuf ============
// Weights pre-swizzled (k0) -> linear DMA + conflict-free reads. p1/p2 are
// wave-local (write rows w*16.., read rows w*16+ln) -> no layer barriers.
__global__ __launch_bounds__(256) void k3_node(
    const float* __restrict__ inputs, const float* __restrict__ AGG,
    const f16* __restrict__ Wf1TS, const float* __restrict__ bf1,
    const f16* __restrict__ Wf2TS, const float* __restrict__ bf2,
    const f16* __restrict__ Wf3TS, const float* __restrict__ bf3,
    float* __restrict__ out)
{
    __shared__ __align__(16) f16 aug[64][328];    // [x(64) | agg(256)] + pad
    __shared__ __align__(16) f16 p1[64][264];
    __shared__ __align__(16) f16 wl[2][256*64];   // B dbuf (swizzled content)
    int tid = threadIdx.x;
    int w = tid >> 6, lane = tid & 63, ln = lane & 15, q = lane >> 4;
    int lrow8 = lane >> 3, lc8 = lane & 7;
    int m0 = blockIdx.x * 64;

    for (int it = 0; it < 10; ++it) {       // stage aug = [x | agg]
        int s = it*256 + tid;
        if (s < 512) {
            int m = s >> 3, hs = s & 7;
            int mrow = m0 + m;
            int b = mrow / 2016, r2 = mrow % 2016, t = r2 >> 5, n = r2 & 31;
            const float* px = &inputs[((b*NN + n)*NT + t)*ND + hs*8];
            f32x4 v0 = *(const f32x4*)px, v1 = *(const f32x4*)(px + 4);
            f16x8 o;
            #pragma unroll
            for (int e = 0; e < 4; ++e) { o[e] = (f16)v0[e]; o[e+4] = (f16)v1[e]; }
            *(f16x8*)&aug[m][hs*8] = o;
        } else {
            int s2 = s - 512;
            int m = s2 >> 5, hs = s2 & 31;
            const float* pa = &AGG[(size_t)(m0 + m)*NSO + hs*8];
            f32x4 v0 = *(const f32x4*)pa, v1 = *(const f32x4*)(pa + 4);
            f16x8 o;
            #pragma unroll
            for (int e = 0; e < 4; ++e) { o[e] = (f16)v0[e]; o[e+4] = (f16)v1[e]; }
            *(f16x8*)&aug[m][64 + hs*8] = o;
        }
    }
    auto stageW1 = [&](int hc, int buf) {        // 32 KB from Wf1TS (stride 320)
        #pragma unroll
        for (int it = 0; it < 8; ++it) {
            int co0 = (it*4 + w)*8;
            gl_lds16(&Wf1TS[(size_t)(co0 + lrow8)*320 + hc*64 + lc8*8],
                     &wl[buf][co0*64 + lane*8]);
        }
    };
    auto stageW2 = [&](int hc, int buf) {        // 32 KB from Wf2TS (stride 256)
        #pragma unroll
        for (int it = 0; it < 8; ++it) {
            int co0 = (it*4 + w)*8;
            gl_lds16(&Wf2TS[(size_t)(co0 + lrow8)*256 + hc*64 + lc8*8],
                     &wl[buf][co0*64 + lane*8]);
        }
    };
    stageW1(0, 0);
    __syncthreads();                             // aug + wl[0] ready

    const f32x4 z4 = {0.f, 0.f, 0.f, 0.f};
    // ---- layer 1: K=320 ----
    f32x4 acc1[16];
    #pragma unroll
    for (int nt = 0; nt < 16; ++nt) acc1[nt] = z4;
    for (int hc = 0; hc < 5; ++hc) {
        int buf = hc & 1;
        if (hc < 4) stageW1(hc + 1, buf ^ 1);
        else        stageW2(0, buf ^ 1);         // prefetch layer2 chunk 0
        const f16* wb = &wl[buf][0];
        #pragma unroll
        for (int ks = 0; ks < 2; ++ks) {
            f16x8 Af = *(const f16x8*)&aug[w*16 + ln][hc*64 + ks*32 + q*8];
            #pragma unroll
            for (int nt = 0; nt < 16; ++nt) {
                f16x8 Bf = *(const f16x8*)&wb[(nt*16 + ln)*64 +
                                (((ks*4 + q) ^ (ln & 7)) << 3)];
                acc1[nt] = __builtin_amdgcn_mfma_f32_16x16x32_f16(Af, Bf, acc1[nt], 0, 0, 0);
            }
        }
        __syncthreads();                         // drains prefetch DMA
    }
    #pragma unroll
    for (int nt = 0; nt < 16; ++nt) {            // p1: wave-local rows
        int co = nt*16 + ln;
        float bias = bf1[co];
        #pragma unroll
        for (int r = 0; r < 4; ++r) {
            float v = acc1[nt][r] + bias; v = v > 0.f ? v : 0.f;
            p1[w*16 + q*4 + r][co] = (f16)v;
        }
    }
    // ---- layer 2: K=256 (chunk 0 already in wl[1]) ----
    f32x4 acc2[16];
    #pragma unroll
    for (int nt = 0; nt < 16; ++nt) acc2[nt] = z4;
    for (int hc = 0; hc < 4; ++hc) {
        int buf = (hc + 1) & 1;                  // 1,0,1,0
        if (hc < 3) stageW2(hc + 1, buf ^ 1);
        const f16* wb = &wl[buf][0];
        #pragma unroll
        for (int ks = 0; ks < 2; ++ks) {
            f16x8 Af = *(const f16x8*)&p1[w*16 + ln][hc*64 + ks*32 + q*8];
            #pragma unroll
            for (int nt = 0; nt < 16; ++nt) {
                f16x8 Bf = *(const f16x8*)&wb[(nt*16 + ln)*64 +
                                (((ks*4 + q) ^ (ln & 7)) << 3)];
                acc2[nt] = __builtin_amdgcn_mfma_f32_16x16x32_f16(Af, Bf, acc2[nt], 0, 0, 0);
            }
        }
        __syncthreads();
    }
    f16* p2 = &aug[0][0];    // reuse aug storage, stride 264 (wave-local rows)
    #pragma unroll
    for (int nt = 0; nt < 16; ++nt) {
        int co = nt*16 + ln;
        float bias = bf2[co];
        #pragma unroll
        for (int r = 0; r < 4; ++r) {
            float v = acc2[nt][r] + bias; v = v > 0.f ? v : 0.f;
            p2[(w*16 + q*4 + r)*264 + co] = (f16)v;
        }
    }
    // ---- layer 3: K=256, N=64; Wf3TS -> wl[0] (64 rows x 256) ----
    {
        #pragma unroll
        for (int it = 0; it < 8; ++it) {
            int d0 = (it*4 + w)*2;
            int lr = lane >> 5, ls = lane & 31;
            gl_lds16(&Wf3TS[(size_t)(d0 + lr)*256 + ls*8],
                     &wl[0][d0*256 + lane*8]);
        }
    }
    __syncthreads();                             // drains W3 DMA
    f32x4 acc3[4];
    #pragma unroll
    for (int nt = 0; nt < 4; ++nt) acc3[nt] = z4;
    #pragma unroll
    for (int ks = 0; ks < 8; ++ks) {
        f16x8 Af = *(const f16x8*)&p2[(w*16 + ln)*264 + ks*32 + q*8];
        #pragma unroll
        for (int nt = 0; nt < 4; ++nt) {
            int pos = ks*4 + q;
            int phys = (pos & 24) | ((pos & 7) ^ (ln & 7));
            f16x8 Bf = *(const f16x8*)&wl[0][(nt*16 + ln)*256 + phys*8];
            acc3[nt] = __builtin_amdgcn_mfma_f32_16x16x32_f16(Af, Bf, acc3[nt], 0, 0, 0);
        }
    }
    #pragma unroll
    for (int nt = 0; nt < 4; ++nt) {
        int d = nt*16 + ln;
        float bias = bf3[d];
        #pragma unroll
        for (int r = 0; r < 4; ++r) {
            int mrow = m0 + w*16 + q*4 + r;
            int b = mrow / 2016, r2 = mrow % 2016, t = r2 >> 5, n = r2 & 31;
            float xv = inputs[((b*NN + n)*NT + t)*ND + d];
            out[((size_t)(b*NN + n)*TOUT + t)*ND + d] = acc3[nt][r] + bias + xv;
        }
    }
}

extern "C" void kernel_launch(void* const* d_in, const int* in_sizes, int n_in,
                              void* d_out, int out_size, void* d_ws, size_t ws_size,
                              hipStream_t stream)
{
    const float* inputs = (const float*)d_in[0];
    const float* rel    = (const float*)d_in[1];
    const float* W1     = (const float*)d_in[4];
    const float* b1     = (const float*)d_in[5];
    const float* W2     = (const float*)d_in[6];
    const float* b2     = (const float*)d_in[7];
    const float* Wf1    = (const float*)d_in[8];
    const float* bf1    = (const float*)d_in[9];
    const float* Wf2    = (const float*)d_in[10];
    const float* bf2    = (const float*)d_in[11];
    const float* Wf3    = (const float*)d_in[12];
    const float* bf3    = (const float*)d_in[13];
    char* ws = (char*)d_ws;
    f16*   Rb    = (f16*)(ws + OFF_R);
    f16*   Sb    = (f16*)(ws + OFF_S);
    f16*   W2T   = (f16*)(ws + OFF_W2T);
    f16*   Wf1TS = (f16*)(ws + OFF_WF1);
    f16*   Wf2TS = (f16*)(ws + OFF_WF2);
    f16*   Wf3TS = (f16*)(ws + OFF_WF3);
    float* REL   = (float*)(ws + OFF_REL);
    float* AGG   = (float*)(ws + OFF_AGG);
    f16*   W1TS  = (f16*)(ws + OFF_W1T);
    float* out   = (float*)d_out;

    hipLaunchKernelGGL(k0_prep, dim3(2304), dim3(256), 0, stream,
                       W1, W2, Wf1, Wf2, Wf3, rel, W1TS, W2T, Wf1TS, Wf2TS, Wf3TS, REL,
                       (unsigned int*)AGG);
    hipLaunchKernelGGL(k1_partials, dim3(252), dim3(256), 0, stream,
                       inputs, W1TS, b1, Rb, Sb);
    hipLaunchKernelGGL(k2_edge, dim3(252), dim3(512), 0, stream,
                       Rb, Sb, W2T, b2, REL, AGG);
    hipLaunchKernelGGL(k3_node, dim3(252), dim3(256), 0, stream,
                       inputs, AGG, Wf1TS, bf1, Wf2TS, bf2, Wf3TS, bf3, out);
}

// Round 13
// 430.256 us; speedup vs baseline: 1.2994x; 1.0469x over previous
//
#include <hip/hip_runtime.h>
#include <hip/hip_fp16.h>

typedef _Float16 f16;
typedef _Float16 f16x8 __attribute__((ext_vector_type(8)));
typedef _Float16 f16x4 __attribute__((ext_vector_type(4)));
typedef float    f32x4 __attribute__((ext_vector_type(4)));

#define AS1 __attribute__((address_space(1)))
#define AS3 __attribute__((address_space(3)))

// async 16B global->LDS DMA: LDS dest is wave-uniform base + lane*16.
__device__ __forceinline__ void gl_lds16(const void* g, void* l) {
    __builtin_amdgcn_global_load_lds((const AS1 unsigned int*)g,
                                     (AS3 unsigned int*)l, 16, 0, 0);
}

#define NB   8
#define NN   32
#define NT   64
#define ND   64
#define NK   4
#define NH   256
#define NSO  256
#define NE   992
#define TOUT 63
#define M1   (NB*TOUT*NN)   // 16128 node-time rows
#define NBT  (NB*TOUT)      // 504 (b,t) pairs

// ---- workspace layout (bytes) ----
static constexpr size_t SZ_RS   = (size_t)M1 * 1024 * 2;        // 33,030,144
static constexpr size_t OFF_R   = 0;
static constexpr size_t OFF_S   = OFF_R + SZ_RS;
static constexpr size_t OFF_W2T = OFF_S + SZ_RS;                // f16 [k][co][h] plain
static constexpr size_t OFF_WF1 = OFF_W2T + 4*256*256*2;        // f16 [co][320] swizzled
static constexpr size_t OFF_WF2 = OFF_WF1 + 256*320*2;          // f16 [co][256] swizzled
static constexpr size_t OFF_WF3 = OFF_WF2 + 256*256*2;          // f16 [d][256] swizzled
static constexpr size_t OFF_REL = OFF_WF3 + 64*256*2;           // f32 [b][ns][k][32]
static constexpr size_t OFF_AGG = OFF_REL + (size_t)NB*NN*NK*32*4; // f32 [m][256]
static constexpr size_t OFF_W1T = OFF_AGG + (size_t)M1*256*4;   // f16 [c(2048)][64] swizzled
// total = OFF_W1T + 262,144 = 83,820,544 bytes

// ============================ K0: weight prep + AGG zero ============================
// W1TS/Wf1TS/Wf2TS: 16B chunks of each 64-col sub-row pre-swizzled by (row&7);
// Wf3TS: 32 chunks, low-3 bits swizzled by (d&7). Linear DMA staging in k1/k3
// then reads at chunk^(ln&7) conflict-free (m136: 2-way is free).
__global__ __launch_bounds__(256) void k0_prep(
    const float* __restrict__ W1, const float* __restrict__ W2,
    const float* __restrict__ Wf1, const float* __restrict__ Wf2,
    const float* __restrict__ Wf3, const float* __restrict__ rel,
    f16* __restrict__ W1TS, f16* __restrict__ W2T, f16* __restrict__ Wf1TS,
    f16* __restrict__ Wf2TS, f16* __restrict__ Wf3TS, float* __restrict__ REL,
    unsigned int* __restrict__ AGGZ)
{
    int id = blockIdx.x * 256 + threadIdx.x;
    if (id < 262144) {                      // W2T[k][co][h] = W2[k][h][co] (plain)
        int k = id >> 16, co = (id >> 8) & 255, h = id & 255;
        W2T[id] = (f16)W2[k*65536 + h*256 + co];
    } else if (id < 344064) {               // Wf1TS[co][dcol], d<320, swizzled
        int i = id - 262144; int co = i / 320, dcol = i % 320;
        int hc = dcol >> 6, c8 = (dcol >> 3) & 7, e = dcol & 7;
        int sd = hc*64 + ((c8 ^ (co & 7)) << 3) + e;
        Wf1TS[i] = (f16)Wf1[sd*256 + co];
    } else if (id < 409600) {               // Wf2TS[co][h], swizzled
        int i = id - 344064; int co = i >> 8, dcol = i & 255;
        int hc = dcol >> 6, c8 = (dcol >> 3) & 7, e = dcol & 7;
        int sh = hc*64 + ((c8 ^ (co & 7)) << 3) + e;
        Wf2TS[i] = (f16)Wf2[sh*256 + co];
    } else if (id < 425984) {               // Wf3TS[d][col], swizzled (32 chunks)
        int i = id - 409600; int d = i >> 8, col = i & 255;
        int c32 = col >> 3, e = col & 7;
        int sc = (c32 & 24) | ((c32 & 7) ^ (d & 7));
        Wf3TS[i] = (f16)Wf3[(sc*8 + e)*64 + d];
    } else if (id < 458752) {               // REL[b][ns][k][j], self-edge -> 0
        int i = id - 425984;
        int j = i & 31, k = (i >> 5) & 3, ns = (i >> 7) & 31, b = i >> 12;
        float v = 0.f;
        if (j != ns) v = rel[(b*NE + ns*31 + (j < ns ? j : j - 1))*NK + k];
        REL[i] = v;
    } else {                                // W1TS[c][dcol], swizzled (131072 elems)
        int i = id - 458752;
        int c = i >> 6, dcol = i & 63;
        int c8 = (dcol >> 3) & 7, e = dcol & 7;
        int sd = ((c8 ^ (c & 7)) << 3) + e;
        int k = c >> 9, dd = (c >> 8) & 1, h = c & 255;
        W1TS[i] = (f16)W1[(k*128 + dd*64 + sd)*NH + h];
    }
    // zero AGG (f32): 4,128,768 dwords = 7 x 589,824 threads exactly
    #pragma unroll
    for (int j = 0; j < 7; ++j) {
        int idx = id + j*589824;
        if (idx < 4128768) AGGZ[idx] = 0u;
    }
}

// ============ K1: per-node layer-1 partials R,S (MFMA, f16, DMA dbuf) ============
// Rb/Sb rows stored with each 64-f16 sub-block's 16B chunks swizzled by n&7
// (n = node = m&31) so k2's LDS reads at chunk^(row&7) are conflict-free.
__global__ __launch_bounds__(256) void k1_partials(
    const float* __restrict__ inputs, const f16* __restrict__ W1TS,
    const float* __restrict__ b1, f16* __restrict__ Rb, f16* __restrict__ Sb)
{
    __shared__ __align__(16) f16 xs[64][72];      // A: 64 rows x 64 d (padded)
    __shared__ __align__(16) f16 wl[2][256*64];   // B dbuf (swizzled content)
    __shared__ __align__(16) f16 ob[64*264];      // out-stage
    int tid = threadIdx.x;
    int w = tid >> 6, lane = tid & 63, ln = lane & 15, q = lane >> 4;
    int lrow8 = lane >> 3, lc8 = lane & 7;
    int m0 = blockIdx.x * 64;

    #pragma unroll
    for (int it = 0; it < 2; ++it) {             // stage x -> f16
        int idx8 = it*256 + tid;
        int m = idx8 >> 3, hs = idx8 & 7;
        int mrow = m0 + m;
        int b = mrow / 2016, r2 = mrow % 2016, t = r2 >> 5, n = r2 & 31;
        const float* px = &inputs[((b*NN + n)*NT + t)*ND + hs*8];
        f32x4 v0 = *(const f32x4*)px, v1 = *(const f32x4*)(px + 4);
        f16x8 o;
        #pragma unroll
        for (int e = 0; e < 4; ++e) { o[e] = (f16)v0[e]; o[e+4] = (f16)v1[e]; }
        *(f16x8*)&xs[m][hs*8] = o;
    }
    auto stageW = [&](int cc, int buf) {         // 32 KB: 8 calls/wave
        #pragma unroll
        for (int it = 0; it < 8; ++it) {
            int co0 = (it*4 + w)*8;
            gl_lds16(&W1TS[(size_t)(cc*256 + co0 + lrow8)*64 + lc8*8],
                     &wl[buf][co0*64 + lane*8]);
        }
    };
    stageW(0, 0);
    __syncthreads();

    const f32x4 z4 = {0.f, 0.f, 0.f, 0.f};
    for (int cc = 0; cc < 8; ++cc) {             // 8 chunks of 256 output cols
        int k = cc >> 1, dd = cc & 1;
        if (cc < 7) stageW(cc + 1, (cc + 1) & 1);
        const f16* wb = &wl[cc & 1][0];
        f32x4 acc[16];
        #pragma unroll
        for (int nt = 0; nt < 16; ++nt) acc[nt] = z4;
        #pragma unroll
        for (int ks = 0; ks < 2; ++ks) {
            f16x8 Af = *(const f16x8*)&xs[w*16 + ln][ks*32 + q*8];
            #pragma unroll
            for (int nt = 0; nt < 16; ++nt) {
                f16x8 Bf = *(const f16x8*)&wb[(nt*16 + ln)*64 +
                                (((ks*4 + q) ^ (ln & 7)) << 3)];
                acc[nt] = __builtin_amdgcn_mfma_f32_16x16x32_f16(Af, Bf, acc[nt], 0, 0, 0);
            }
        }
        #pragma unroll
        for (int nt = 0; nt < 16; ++nt) {
            int co = nt*16 + ln;
            float bias = dd ? b1[k*NH + co] : 0.f;
            #pragma unroll
            for (int r = 0; r < 4; ++r) {
                float v = acc[nt][r] + bias;
                ob[(w*16 + q*4 + r)*264 + co] = (f16)v;
            }
        }
        __syncthreads();                          // ob ready; DMA(cc+1) drained
        f16* dst = dd ? Sb : Rb;
        #pragma unroll
        for (int it = 0; it < 8; ++it) {          // swizzled coalesced stores
            int idx8 = it*256 + tid;
            int m = idx8 >> 5, seg = idx8 & 31;
            int hcb = seg >> 3, c = seg & 7;
            *(f16x8*)&dst[(size_t)(m0 + m)*1024 + k*256 + hcb*64 + c*8] =
                *(const f16x8*)&ob[m*264 + hcb*64 + (((c ^ (m & 7))) << 3)];
        }
        __syncthreads();                          // ob reuse
    }
}

// ============ K2: edge MLP layer-2, W2 resident in REGISTERS ============
// VERBATIM round-7 measured form (349 us): bias in epilogue (NOT folded into
// acc init -- fold variants r11/r12 measured 3-5% slower, likely the 16 extra
// live VGPRs at 192-reg pressure), scalar-ternary A-build, z4 acc init.
// Block = (k, bt-chunk of 8): grid 252, 512 thr, 1 block/CU, 2 waves/SIMD
// (structural: Breg 128 + acc 64). Plateau: r7-r12 variants all 349-447.
__global__ __launch_bounds__(512, 2) void k2_edge(
    const f16* __restrict__ Rb, const f16* __restrict__ Sb,
    const f16* __restrict__ W2T, const float* __restrict__ b2,
    const float* __restrict__ REL, float* __restrict__ AGG)
{
    __shared__ __align__(16) f16 Rbuf[2][32*256];
    __shared__ __align__(16) f16 Sbuf[2][4*256];
    int tid = threadIdx.x;
    int blk = blockIdx.x;
    int k = blk & 3, g = blk >> 2;               // g in 0..62 -> bt = g*8..g*8+7
    int w = tid >> 6, lane = tid & 63, ln = lane & 15, q = lane >> 4;
    int mg = w >> 2, ng = w & 3;
    int lrow = lane >> 5, lseg = lane & 31;      // DMA: 2 rows x 32 chunks per call

    // ---- W2(k) fragments in registers + bias ----
    f16x8 Breg[4][8];
    float bias[4];
    #pragma unroll
    for (int nt = 0; nt < 4; ++nt) {
        int co = ng*64 + nt*16 + ln;
        bias[nt] = b2[k*256 + co];
        const f16* wrow = &W2T[(size_t)(k*256 + co)*256];
        #pragma unroll
        for (int ks = 0; ks < 8; ++ks)
            Breg[nt][ks] = *(const f16x8*)&wrow[ks*32 + q*8];
    }

    auto stageR = [&](int bt, int buf) {         // 16 KB: 16 calls (2/wave)
        #pragma unroll
        for (int it = 0; it < 2; ++it) {
            int rowbase = (w*2 + it)*2;
            gl_lds16(&Rb[((size_t)bt*NN + rowbase + lrow)*1024 + k*256 + lseg*8],
                     &Rbuf[buf][rowbase*256 + lane*8]);
        }
    };
    auto stageS = [&](int i, int buf) {          // 2 KB: 2 calls (waves 0,1)
        int bt = g*8 + (i >> 3), nsq = i & 7;
        if (w < 2)
            gl_lds16(&Sb[((size_t)bt*NN + nsq*4 + w*2 + lrow)*1024 + k*256 + lseg*8],
                     &Sbuf[buf][(w*2)*256 + lane*8]);
    };

    stageR(g*8, 0);
    stageS(0, 0);
    __syncthreads();

    const f32x4 z4 = {0.f, 0.f, 0.f, 0.f};
    for (int i = 0; i < 64; ++i) {
        int ibt = i >> 3, nsq = i & 7;
        int bt = g*8 + ibt, b = bt / TOUT;
        int rb = ibt & 1, sb = i & 1;
        if (i < 63) stageS(i + 1, sb ^ 1);
        if (nsq == 6 && ibt < 7) stageR(bt + 1, rb ^ 1);

        const f16* Rl = &Rbuf[rb][0];
        const f16* Sl = &Sbuf[sb][0];
        int ns0 = nsq*4 + mg*2;                  // this wave's first sender
        f32x4 acc[4][4];
        #pragma unroll
        for (int mt = 0; mt < 4; ++mt)
            #pragma unroll
            for (int nt = 0; nt < 4; ++nt) acc[mt][nt] = z4;

        #pragma unroll
        for (int ks = 0; ks < 8; ++ks) {
            int hc = ks >> 1;
            int c4 = (ks & 1)*4 + q;
            int paR = hc*64 + ((c4 ^ (ln & 7)) << 3);
            f16x8 rlo = *(const f16x8*)&Rl[ln*256 + paR];
            f16x8 rhi = *(const f16x8*)&Rl[(16 + ln)*256 + paR];
            f16x8 s0 = *(const f16x8*)&Sl[(mg*2 + 0)*256 + hc*64 + ((c4 ^ (ns0 & 7)) << 3)];
            f16x8 s1 = *(const f16x8*)&Sl[(mg*2 + 1)*256 + hc*64 + ((c4 ^ ((ns0 + 1) & 7)) << 3)];
            f16x8 A[4];
            #pragma unroll
            for (int mt = 0; mt < 4; ++mt) {
                f16x8 rr = (mt & 1) ? rhi : rlo;
                f16x8 ss = (mt >> 1) ? s1 : s0;
                f16x8 v;
                #pragma unroll
                for (int e = 0; e < 8; ++e) {
                    f16 x = rr[e] + ss[e];
                    v[e] = x > (f16)0 ? x : (f16)0;
                }
                A[mt] = v;
            }
            #pragma unroll
            for (int nt = 0; nt < 4; ++nt) {
                f16x8 Bf = Breg[nt][ks];
                #pragma unroll
                for (int mt = 0; mt < 4; ++mt)
                    acc[mt][nt] = __builtin_amdgcn_mfma_f32_16x16x32_f16(
                        A[mt], Bf, acc[mt][nt], 0, 0, 0);
            }
        }
        // epilogue: bias+relu, rel-weight, reduce over 32 j, f32 atomic add
        #pragma unroll
        for (int half = 0; half < 2; ++half) {
            int ns = ns0 + half;
            const float* relp = &REL[(((size_t)b*NN + ns)*NK + k)*32];
            f32x4 rel0 = *(const f32x4*)&relp[q*4];
            f32x4 rel1 = *(const f32x4*)&relp[16 + q*4];
            #pragma unroll
            for (int nt = 0; nt < 4; ++nt) {
                float s = 0.f;
                #pragma unroll
                for (int r = 0; r < 4; ++r) {
                    float v0 = acc[2*half + 0][nt][r] + bias[nt];
                    float v1 = acc[2*half + 1][nt][r] + bias[nt];
                    v0 = v0 > 0.f ? v0 : 0.f;
                    v1 = v1 > 0.f ? v1 : 0.f;
                    s += v0 * rel0[r] + v1 * rel1[r];
                }
                s += __shfl_xor(s, 16);
                s += __shfl_xor(s, 32);
                if (lane < 16)
                    atomicAdd(&AGG[((size_t)bt*NN + ns)*256 + ng*64 + nt*16 + lane], s);
            }
        }
        __syncthreads();
    }
}

// ============ K3: node MLP (320->256->256->64) + residual, DMA dbuf ============
__global__ __launch_bounds__(256) void k3_node(
    const float* __restrict__ inputs, const float* __restrict__ AGG,
    const f16* __restrict__ Wf1TS, const float* __restrict__ bf1,
    const f16* __restrict__ Wf2TS, const float* __restrict__ bf2,
    const f16* __restrict__ Wf3TS, const float* __restrict__ bf3,
    float* __restrict__ out)
{
    __shared__ __align__(16) f16 aug[64][328];    // [x(64) | agg(256)] + pad
    __shared__ __align__(16) f16 p1[64][264];
    __shared__ __align__(16) f16 wl[2][256*64];   // B dbuf (swizzled content)
    int tid = threadIdx.x;
    int w = tid >> 6, lane = tid & 63, ln = lane & 15, q = lane >> 4;
    int lrow8 = lane >> 3, lc8 = lane & 7;
    int m0 = blockIdx.x * 64;

    for (int it = 0; it < 10; ++it) {       // stage aug = [x | agg]
        int s = it*256 + tid;
        if (s < 512) {
            int m = s >> 3, hs = s & 7;
            int mrow = m0 + m;
            int b = mrow / 2016, r2 = mrow % 2016, t = r2 >> 5, n = r2 & 31;
            const float* px = &inputs[((b*NN + n)*NT + t)*ND + hs*8];
            f32x4 v0 = *(const f32x4*)px, v1 = *(const f32x4*)(px + 4);
            f16x8 o;
            #pragma unroll
            for (int e = 0; e < 4; ++e) { o[e] = (f16)v0[e]; o[e+4] = (f16)v1[e]; }
            *(f16x8*)&aug[m][hs*8] = o;
        } else {
            int s2 = s - 512;
            int m = s2 >> 5, hs = s2 & 31;
            const float* pa = &AGG[(size_t)(m0 + m)*NSO + hs*8];
            f32x4 v0 = *(const f32x4*)pa, v1 = *(const f32x4*)(pa + 4);
            f16x8 o;
            #pragma unroll
            for (int e = 0; e < 4; ++e) { o[e] = (f16)v0[e]; o[e+4] = (f16)v1[e]; }
            *(f16x8*)&aug[m][64 + hs*8] = o;
        }
    }
    auto stageW1 = [&](int hc, int buf) {        // 32 KB from Wf1TS (stride 320)
        #pragma unroll
        for (int it = 0; it < 8; ++it) {
            int co0 = (it*4 + w)*8;
            gl_lds16(&Wf1TS[(size_t)(co0 + lrow8)*320 + hc*64 + lc8*8],
                     &wl[buf][co0*64 + lane*8]);
        }
    };
    auto stageW2 = [&](int hc, int buf) {        // 32 KB from Wf2TS (stride 256)
        #pragma unroll
        for (int it = 0; it < 8; ++it) {
            int co0 = (it*4 + w)*8;
            gl_lds16(&Wf2TS[(size_t)(co0 + lrow8)*256 + hc*64 + lc8*8],
                     &wl[buf][co0*64 + lane*8]);
        }
    };
    stageW1(0, 0);
    __syncthreads();                             // aug + wl[0] ready

    const f32x4 z4 = {0.f, 0.f, 0.f, 0.f};
    // ---- layer 1: K=320 ----
    f32x4 acc1[16];
    #pragma unroll
    for (int nt = 0; nt < 16; ++nt) acc1[nt] = z4;
    for (int hc = 0; hc < 5; ++hc) {
        int buf = hc & 1;
        if (hc < 4) stageW1(hc + 1, buf ^ 1);
        else        stageW2(0, buf ^ 1);         // prefetch layer2 chunk 0
        const f16* wb = &wl[buf][0];
        #pragma unroll
        for (int ks = 0; ks < 2; ++ks) {
            f16x8 Af = *(const f16x8*)&aug[w*16 + ln][hc*64 + ks*32 + q*8];
            #pragma unroll
            for (int nt = 0; nt < 16; ++nt) {
                f16x8 Bf = *(const f16x8*)&wb[(nt*16 + ln)*64 +
                                (((ks*4 + q) ^ (ln & 7)) << 3)];
                acc1[nt] = __builtin_amdgcn_mfma_f32_16x16x32_f16(Af, Bf, acc1[nt], 0, 0, 0);
            }
        }
        __syncthreads();                         // drains prefetch DMA
    }
    #pragma unroll
    for (int nt = 0; nt < 16; ++nt) {            // p1: wave-local rows
        int co = nt*16 + ln;
        float bias = bf1[co];
        #pragma unroll
        for (int r = 0; r < 4; ++r) {
            float v = acc1[nt][r] + bias; v = v > 0.f ? v : 0.f;
            p1[w*16 + q*4 + r][co] = (f16)v;
        }
    }
    // ---- layer 2: K=256 (chunk 0 already in wl[1]) ----
    f32x4 acc2[16];
    #pragma unroll
    for (int nt = 0; nt < 16; ++nt) acc2[nt] = z4;
    for (int hc = 0; hc < 4; ++hc) {
        int buf = (hc + 1) & 1;                  // 1,0,1,0
        if (hc < 3) stageW2(hc + 1, buf ^ 1);
        const f16* wb = &wl[buf][0];
        #pragma unroll
        for (int ks = 0; ks < 2; ++ks) {
            f16x8 Af = *(const f16x8*)&p1[w*16 + ln][hc*64 + ks*32 + q*8];
            #pragma unroll
            for (int nt = 0; nt < 16; ++nt) {
                f16x8 Bf = *(const f16x8*)&wb[(nt*16 + ln)*64 +
                                (((ks*4 + q) ^ (ln & 7)) << 3)];
                acc2[nt] = __builtin_amdgcn_mfma_f32_16x16x32_f16(Af, Bf, acc2[nt], 0, 0, 0);
            }
        }
        __syncthreads();
    }
    f16* p2 = &aug[0][0];    // reuse aug storage, stride 264 (wave-local rows)
    #pragma unroll
    for (int nt = 0; nt < 16; ++nt) {
        int co = nt*16 + ln;
        float bias = bf2[co];
        #pragma unroll
        for (int r = 0; r < 4; ++r) {
            float v = acc2[nt][r] + bias; v = v > 0.f ? v : 0.f;
            p2[(w*16 + q*4 + r)*264 + co] = (f16)v;
        }
    }
    // ---- layer 3: K=256, N=64; Wf3TS -> wl[0] (64 rows x 256) ----
    {
        #pragma unroll
        for (int it = 0; it < 8; ++it) {
            int d0 = (it*4 + w)*2;
            int lr = lane >> 5, ls = lane & 31;
            gl_lds16(&Wf3TS[(size_t)(d0 + lr)*256 + ls*8],
                     &wl[0][d0*256 + lane*8]);
        }
    }
    __syncthreads();                             // drains W3 DMA
    f32x4 acc3[4];
    #pragma unroll
    for (int nt = 0; nt < 4; ++nt) acc3[nt] = z4;
    #pragma unroll
    for (int ks = 0; ks < 8; ++ks) {
        f16x8 Af = *(const f16x8*)&p2[(w*16 + ln)*264 + ks*32 + q*8];
        #pragma unroll
        for (int nt = 0; nt < 4; ++nt) {
            int pos = ks*4 + q;
            int phys = (pos & 24) | ((pos & 7) ^ (ln & 7));
            f16x8 Bf = *(const f16x8*)&wl[0][(nt*16 + ln)*256 + phys*8];
            acc3[nt] = __builtin_amdgcn_mfma_f32_16x16x32_f16(Af, Bf, acc3[nt], 0, 0, 0);
        }
    }
    #pragma unroll
    for (int nt = 0; nt < 4; ++nt) {
        int d = nt*16 + ln;
        float bias = bf3[d];
        #pragma unroll
        for (int r = 0; r < 4; ++r) {
            int mrow = m0 + w*16 + q*4 + r;
            int b = mrow / 2016, r2 = mrow % 2016, t = r2 >> 5, n = r2 & 31;
            float xv = inputs[((b*NN + n)*NT + t)*ND + d];
            out[((size_t)(b*NN + n)*TOUT + t)*ND + d] = acc3[nt][r] + bias + xv;
        }
    }
}

extern "C" void kernel_launch(void* const* d_in, const int* in_sizes, int n_in,
                              void* d_out, int out_size, void* d_ws, size_t ws_size,
                              hipStream_t stream)
{
    const float* inputs = (const float*)d_in[0];
    const float* rel    = (const float*)d_in[1];
    const float* W1     = (const float*)d_in[4];
    const float* b1     = (const float*)d_in[5];
    const float* W2     = (const float*)d_in[6];
    const float* b2     = (const float*)d_in[7];
    const float* Wf1    = (const float*)d_in[8];
    const float* bf1    = (const float*)d_in[9];
    const float* Wf2    = (const float*)d_in[10];
    const float* bf2    = (const float*)d_in[11];
    const float* Wf3    = (const float*)d_in[12];
    const float* bf3    = (const float*)d_in[13];
    char* ws = (char*)d_ws;
    f16*   Rb    = (f16*)(ws + OFF_R);
    f16*   Sb    = (f16*)(ws + OFF_S);
    f16*   W2T   = (f16*)(ws + OFF_W2T);
    f16*   Wf1TS = (f16*)(ws + OFF_WF1);
    f16*   Wf2TS = (f16*)(ws + OFF_WF2);
    f16*   Wf3TS = (f16*)(ws + OFF_WF3);
    float* REL   = (float*)(ws + OFF_REL);
    float* AGG   = (float*)(ws + OFF_AGG);
    f16*   W1TS  = (f16*)(ws + OFF_W1T);
    float* out   = (float*)d_out;

    hipLaunchKernelGGL(k0_prep, dim3(2304), dim3(256), 0, stream,
                       W1, W2, Wf1, Wf2, Wf3, rel, W1TS, W2T, Wf1TS, Wf2TS, Wf3TS, REL,
                       (unsigned int*)AGG);
    hipLaunchKernelGGL(k1_partials, dim3(252), dim3(256), 0, stream,
                       inputs, W1TS, b1, Rb, Sb);
    hipLaunchKernelGGL(k2_edge, dim3(252), dim3(512), 0, stream,
                       Rb, Sb, W2T, b2, REL, AGG);
    hipLaunchKernelGGL(k3_node, dim3(252), dim3(256), 0, stream,
                       inputs, AGG, Wf1TS, bf1, Wf2TS, bf2, Wf3TS, bf3, out);
}